// Round 5
// baseline (61649.011 us; speedup 1.0000x reference)
//
#include <hip/hip_runtime.h>
#include <math.h>

constexpr int BATCH = 16384;
constexpr int CDIM  = 512;
constexpr int HDIM  = 1024;
constexpr int GDIM  = 4096;   // 4*H
constexpr int HEXT  = 1056;   // HDIM + 4 extra + 28 zero-pad (mult of 32)
constexpr int TSTEP = 60;
// gates GEMM concatenated-K layout (split-fp16 compensation):
//   phase1 (lo-cross, acc scaled by 2^-11 afterwards):
//     [0,1056)    W_lo(h-block, pre-scaled 2^11) x A=h_hi
//     [1056,2112) W_hi(h-block)                  x A=h_lo (pre-scaled 2^11)
//     [2112,2624) Wc_lo(ctx, pre-scaled)         x A=ctx_hi
//     [2624,3136) Wc_hi(ctx)                     x A=ctx_lo (pre-scaled)
//   phase2 (hi main):
//     [3136,4192) W_hi(h-block)                  x A=h_hi
//     [4192,4704) Wc_hi(ctx)                     x A=ctx_hi
constexpr int KG1 = 3136;     // phase-1 length
constexpr int KGT = 4704;     // total gates K
constexpr float LOSC  = 2048.0f;       // 2^11
constexpr float ILOSC = 1.0f / 2048.0f;

typedef _Float16 half_t;
typedef _Float16 halfx8 __attribute__((ext_vector_type(8)));
typedef _Float16 halfx4 __attribute__((ext_vector_type(4)));
typedef float    f32x4  __attribute__((ext_vector_type(4)));

__device__ __forceinline__ void async_cp16(const void* g, void* l) {
  __builtin_amdgcn_global_load_lds((__attribute__((address_space(1))) void*)g,
                                   (__attribute__((address_space(3))) void*)l,
                                   16, 0, 0);
}

__device__ __forceinline__ float4 load4h(const half_t* p) {
  halfx4 v = *(const halfx4*)p;
  return make_float4((float)v.x, (float)v.y, (float)v.z, (float)v.w);
}
__device__ __forceinline__ void store4h(half_t* p, float a, float b, float c, float d) {
  halfx4 v = { (_Float16)a, (_Float16)b, (_Float16)c, (_Float16)d };
  *(halfx4*)p = v;
}
__device__ __forceinline__ half_t hi16(float x) { return (half_t)x; }
__device__ __forceinline__ half_t lo16(float x) {    // pre-scaled residual
  return (half_t)((x - (float)((half_t)x)) * LOSC);
}
__device__ __forceinline__ float sigf(float x) { return 1.0f / (1.0f + expf(-x)); }
__device__ __forceinline__ float geluf(float v) {
  return 0.5f * v * (1.0f + erff(v * 0.70710678118f));
}

// ---------- one BK=32 step of the m97 GEMM core ----------
__device__ __forceinline__ void kstep(f32x4 (&acc)[4][4],
    const half_t* __restrict__ A, size_t lda, int krel,
    const half_t* __restrict__ W, size_t ldw, int kw,
    half_t* sA, half_t* sB, int bm0, int bn0) {
  const int tid  = threadIdx.x;
  const int lane = tid & 63;
  const int wave = tid >> 6;
  const int wm = wave >> 1, wn = wave & 1;
  const int ar = lane >> 2;
  const int ak = (lane & 3) * 8;
  const int quad = lane >> 4;
  const int lcol = lane & 15;
#pragma unroll
  for (int cc = 0; cc < 2; ++cc) {
    const int chunk = wave + cc * 4;
    async_cp16(A + (size_t)(bm0 + chunk * 16 + ar) * lda + (krel + ak), sA + chunk * 512);
    async_cp16(W + (size_t)(bn0 + chunk * 16 + ar) * ldw + (kw + ak), sB + chunk * 512);
  }
  asm volatile("s_waitcnt vmcnt(0)" ::: "memory");
  __syncthreads();
  halfx8 af[4], bfr[4];
#pragma unroll
  for (int mi = 0; mi < 4; ++mi)
    af[mi] = *(const halfx8*)&sA[(wm * 64 + mi * 16 + lcol) * 32 + quad * 8];
#pragma unroll
  for (int ni = 0; ni < 4; ++ni)
    bfr[ni] = *(const halfx8*)&sB[(wn * 64 + ni * 16 + lcol) * 32 + quad * 8];
#pragma unroll
  for (int mi = 0; mi < 4; ++mi)
#pragma unroll
    for (int ni = 0; ni < 4; ++ni)
      acc[mi][ni] = __builtin_amdgcn_mfma_f32_16x16x32_f16(af[mi], bfr[ni], acc[mi][ni], 0, 0, 0);
  __syncthreads();
}

__device__ __forceinline__ void scale_acc(f32x4 (&acc)[4][4], float s) {
#pragma unroll
  for (int i = 0; i < 4; ++i)
#pragma unroll
    for (int j = 0; j < 4; ++j) acc[i][j] *= s;
}

// ---------- preamble GEMM (split-K 1536): C = tanh(ctx @ Wcat^T + bias) ----------
template <bool SPLITOUT>
__global__ __launch_bounds__(256, 2)
void gemm3_pre(const half_t* __restrict__ Ahi, const half_t* __restrict__ Alo,
               const half_t* __restrict__ Wcat, const float* __restrict__ bias,
               float* __restrict__ Cf, half_t* __restrict__ Chi, half_t* __restrict__ Clo) {
  __shared__ __align__(16) half_t sA[128 * 32];
  __shared__ __align__(16) half_t sB[128 * 32];
  const int tid = threadIdx.x;
  const int bm0 = blockIdx.x * 128, bn0 = blockIdx.y * 128;
  f32x4 acc[4][4];
#pragma unroll
  for (int i = 0; i < 4; ++i)
#pragma unroll
    for (int j = 0; j < 4; ++j) acc[i][j] = (f32x4){0.f, 0.f, 0.f, 0.f};
#pragma unroll 1
  for (int k0 = 0; k0 < 1024; k0 += 32) {
    const half_t* A = (k0 < 512) ? Ahi : Alo;
    kstep(acc, A, CDIM, k0 & 511, Wcat, 1536, k0, sA, sB, bm0, bn0);
  }
  scale_acc(acc, ILOSC);
#pragma unroll 1
  for (int k0 = 1024; k0 < 1536; k0 += 32)
    kstep(acc, Ahi, CDIM, k0 - 1024, Wcat, 1536, k0, sA, sB, bm0, bn0);

  const int lane = tid & 63, wave = tid >> 6;
  const int wm = wave >> 1, wn = wave & 1, quad = lane >> 4, lcol = lane & 15;
#pragma unroll
  for (int ni = 0; ni < 4; ++ni) {
    const int col = bn0 + wn * 64 + ni * 16 + lcol;
    const float bv = bias[col];
#pragma unroll
    for (int mi = 0; mi < 4; ++mi) {
      const int row0 = bm0 + wm * 64 + mi * 16 + quad * 4;
#pragma unroll
      for (int r = 0; r < 4; ++r) {
        const float v = tanhf(acc[mi][ni][r] + bv);
        if (SPLITOUT) {
          const size_t idx = (size_t)(row0 + r) * HEXT + col;
          Chi[idx] = hi16(v);
          Clo[idx] = lo16(v);
        } else {
          Cf[(size_t)(row0 + r) * HDIM + col] = v;
        }
      }
    }
  }
}

// ---------- fused gates GEMM (split-K 4704) + LSTM cell ----------
__global__ __launch_bounds__(256, 2)
void gemm_gates_cell(const half_t* __restrict__ hAhi, const half_t* __restrict__ hAlo,
                     const half_t* __restrict__ ctxhi, const half_t* __restrict__ ctxlo,
                     const half_t* __restrict__ Whh, const float* __restrict__ bias_i,
                     float* __restrict__ c, half_t* __restrict__ hBhi,
                     half_t* __restrict__ hBlo) {
  __shared__ __align__(16) half_t sA[128 * 32];
  __shared__ __align__(16) half_t sB[128 * 32];
  __shared__ __align__(16) float sE[4][16 * 68];
  const int tid = threadIdx.x;
  const int bm0 = blockIdx.x * 128, bn0 = blockIdx.y * 128;
  f32x4 acc[4][4];
#pragma unroll
  for (int i = 0; i < 4; ++i)
#pragma unroll
    for (int j = 0; j < 4; ++j) acc[i][j] = (f32x4){0.f, 0.f, 0.f, 0.f};

#pragma unroll 1
  for (int k0 = 0; k0 < KG1; k0 += 32) {
    const half_t* A; size_t lda; int krel;
    if (k0 < 2112) { lda = HEXT; A = (k0 < 1056) ? hAhi : hAlo;
                     krel = (k0 < 1056) ? k0 : k0 - 1056; }
    else           { lda = CDIM; A = (k0 < 2624) ? ctxhi : ctxlo;
                     krel = (k0 < 2624) ? k0 - 2112 : k0 - 2624; }
    kstep(acc, A, lda, krel, Whh, KGT, k0, sA, sB, bm0, bn0);
  }
  scale_acc(acc, ILOSC);
#pragma unroll 1
  for (int k0 = KG1; k0 < KGT; k0 += 32) {
    const half_t* A; size_t lda; int krel;
    if (k0 < 4192) { lda = HEXT; A = hAhi; krel = k0 - 3136; }
    else           { lda = CDIM; A = ctxhi; krel = k0 - 4192; }
    kstep(acc, A, lda, krel, Whh, KGT, k0, sA, sB, bm0, bn0);
  }

  const int lane = tid & 63, wave = tid >> 6;
  const int wm = wave >> 1, wn = wave & 1, quad = lane >> 4, lcol = lane & 15;
  float* myE = sE[wave];
  const int u = lane & 15;
  const int q = lane >> 4;
  const int jbase = (bn0 + wn * 64) >> 2;

#pragma unroll
  for (int mi = 0; mi < 4; ++mi) {
#pragma unroll
    for (int ni = 0; ni < 4; ++ni)
#pragma unroll
      for (int r = 0; r < 4; ++r)
        myE[(quad * 4 + r) * 68 + ni * 16 + lcol] = acc[mi][ni][r];
    // same-wave DS ops are in-order: reads below see the writes above
#pragma unroll
    for (int k = 0; k < 4; ++k) {
      const int rr = q + 4 * k;
      const int row = bm0 + wm * 64 + mi * 16 + rr;
      const f32x4 gv = *(const f32x4*)&myE[rr * 68 + u * 4];  // {i,f,g,o} pre
      const int j = jbase + u;
      const float4 bb = *(const float4*)(bias_i + 4 * j);
      const float pi = gv[0] + bb.x;
      const float pf = gv[1] + bb.y;
      const float pg = gv[2] + bb.z;
      const float po = gv[3] + bb.w;
      const size_t cidx = (size_t)row * HDIM + j;
      const float cn = sigf(pf) * c[cidx] + sigf(pi) * tanhf(pg);
      c[cidx] = cn;
      const float vh = sigf(po) * tanhf(cn);
      const size_t hidx = (size_t)row * HEXT + j;
      hBhi[hidx] = hi16(vh);
      hBlo[hidx] = lo16(vh);
    }
  }
}

// ---------- MLP GEMM (split-K 3072): LN folded, gelu + W2-dot fused ----------
__global__ __launch_bounds__(256, 2)
void gemm_mlp(const half_t* __restrict__ hBhi, const half_t* __restrict__ hBlo,
              const half_t* __restrict__ W1g, const float* __restrict__ stats,
              const float* __restrict__ v1, const float* __restrict__ v2,
              const float* __restrict__ W2, float* __restrict__ delta) {
  __shared__ __align__(16) half_t sA[128 * 32];
  __shared__ __align__(16) half_t sB[128 * 32];
  const int tid = threadIdx.x;
  const int bm0 = blockIdx.x * 128, bn0 = blockIdx.y * 128;
  f32x4 acc[4][4];
#pragma unroll
  for (int i = 0; i < 4; ++i)
#pragma unroll
    for (int j = 0; j < 4; ++j) acc[i][j] = (f32x4){0.f, 0.f, 0.f, 0.f};
#pragma unroll 1
  for (int k0 = 0; k0 < 2048; k0 += 32) {
    const half_t* A = (k0 < 1024) ? hBhi : hBlo;
    kstep(acc, A, HEXT, k0 & 1023, W1g, 3072, k0, sA, sB, bm0, bn0);
  }
  scale_acc(acc, ILOSC);
#pragma unroll 1
  for (int k0 = 2048; k0 < 3072; k0 += 32)
    kstep(acc, hBhi, HEXT, k0 - 2048, W1g, 3072, k0, sA, sB, bm0, bn0);

  const int lane = tid & 63, wave = tid >> 6;
  const int wm = wave >> 1, wn = wave & 1, quad = lane >> 4, lcol = lane & 15;
  float w2a[4], w2b[4], v1c[4], v2c[4];
#pragma unroll
  for (int ni = 0; ni < 4; ++ni) {
    const int col = bn0 + wn * 64 + ni * 16 + lcol;
    w2a[ni] = W2[col]; w2b[ni] = W2[HDIM + col];
    v1c[ni] = v1[col]; v2c[ni] = v2[col];
  }
#pragma unroll
  for (int mi = 0; mi < 4; ++mi) {
#pragma unroll
    for (int r = 0; r < 4; ++r) {
      const int row = bm0 + wm * 64 + mi * 16 + quad * 4 + r;
      const float mu = stats[2 * row], rs = stats[2 * row + 1];
      float d0 = 0.f, d1 = 0.f;
#pragma unroll
      for (int ni = 0; ni < 4; ++ni) {
        const float g = geluf(rs * (acc[mi][ni][r] - mu * v1c[ni]) + v2c[ni]);
        d0 += g * w2a[ni];
        d1 += g * w2b[ni];
      }
#pragma unroll
      for (int m = 1; m < 16; m <<= 1) {
        d0 += __shfl_xor(d0, m, 64);
        d1 += __shfl_xor(d1, m, 64);
      }
      if (lcol == 0) {
        atomicAdd(&delta[2 * row], d0);
        atomicAdd(&delta[2 * row + 1], d1);
      }
    }
  }
}

// ---------- per-row layernorm stats (+ delta zeroing) ----------
__global__ __launch_bounds__(256)
void ln_stats(const half_t* __restrict__ hhi, const half_t* __restrict__ hlo,
              float* __restrict__ stats, float* __restrict__ delta) {
  const int b = blockIdx.x;
  const int tid = threadIdx.x;
  const size_t off = (size_t)b * HEXT + tid * 4;
  const float4 a = load4h(hhi + off);
  const float4 l = load4h(hlo + off);
  const float x0 = a.x + l.x * ILOSC, x1 = a.y + l.y * ILOSC;
  const float x2 = a.z + l.z * ILOSC, x3 = a.w + l.w * ILOSC;
  float sum = x0 + x1 + x2 + x3;
  float sq  = x0*x0 + x1*x1 + x2*x2 + x3*x3;
#pragma unroll
  for (int off2 = 32; off2 > 0; off2 >>= 1) {
    sum += __shfl_down(sum, off2, 64);
    sq  += __shfl_down(sq,  off2, 64);
  }
  __shared__ float sS[4], sQ[4];
  const int wv = tid >> 6, ln = tid & 63;
  if (ln == 0) { sS[wv] = sum; sQ[wv] = sq; }
  __syncthreads();
  if (tid == 0) {
    const float S = sS[0] + sS[1] + sS[2] + sS[3];
    const float Q = sQ[0] + sQ[1] + sQ[2] + sQ[3];
    const float mu = S * (1.0f / HDIM);
    const float var = Q * (1.0f / HDIM) - mu * mu;
    stats[2 * b]     = mu;
    stats[2 * b + 1] = rsqrtf(var + 1e-5f);
    delta[2 * b]     = 0.f;
    delta[2 * b + 1] = 0.f;
  }
}

// ---------- pos update + out write + next-step extra ----------
__global__ __launch_bounds__(256)
void finalize_step(const float* __restrict__ delta, const float* __restrict__ b2,
                   float* __restrict__ pos, float* __restrict__ out,
                   half_t* __restrict__ hNhi, half_t* __restrict__ hNlo,
                   int t, int M) {
  const int b = blockIdx.x * 256 + threadIdx.x;
  if (b >= M) return;
  const float dx = delta[2*b]   + b2[0];
  const float dy = delta[2*b+1] + b2[1];
  const float px = pos[2*b] + dx, py = pos[2*b+1] + dy;
  pos[2*b] = px; pos[2*b+1] = py;
  out[((size_t)b * TSTEP + t) * 2 + 0] = px;
  out[((size_t)b * TSTEP + t) * 2 + 1] = py;
  const float nrm = fmaxf(sqrtf(dx*dx + dy*dy), 1e-6f);
  const float hx = dx / nrm, hy = dy / nrm;
  const size_t e = (size_t)b * HEXT + HDIM;
  halfx4 ehi = { hi16(dx), hi16(dy), hi16(hx), hi16(hy) };
  halfx4 elo = { lo16(dx), lo16(dy), lo16(hx), lo16(hy) };
  *(halfx4*)(hNhi + e) = ehi;
  *(halfx4*)(hNlo + e) = elo;
}

// ---------- builders ----------
__global__ __launch_bounds__(256)
void cvt_split(const float* __restrict__ s, half_t* __restrict__ dhi,
               half_t* __restrict__ dlo, int n4) {
  int i = blockIdx.x * 256 + threadIdx.x;
  if (i >= n4) return;
  const float4 v = ((const float4*)s)[i];
  halfx4 h = { hi16(v.x), hi16(v.y), hi16(v.z), hi16(v.w) };
  halfx4 l = { lo16(v.x), lo16(v.y), lo16(v.z), lo16(v.w) };
  *(halfx4*)(dhi + (size_t)i * 4) = h;
  *(halfx4*)(dlo + (size_t)i * 4) = l;
}

// Whh_cat [4096][4704] per the phase layout at top of file.
__global__ __launch_bounds__(256)
void build_whh_cat(const float* __restrict__ Whh, const float* __restrict__ Wih,
                   half_t* __restrict__ dst) {
  int idx = blockIdx.x * 256 + threadIdx.x;
  if (idx >= GDIM * (KGT / 4)) return;
  const int rp = idx / (KGT / 4);
  const int k  = (idx - rp * (KGT / 4)) * 4;
  const int sr = (rp & 3) * HDIM + (rp >> 2);
  bool lo; float4 v; bool zero = false;
  if (k < 2112) {                       // h-block: lo then hi
    lo = (k < 1056);
    const int kk = lo ? k : k - 1056;
    if (kk < 1024)          v = *(const float4*)(Whh + (size_t)sr * HDIM + kk);
    else if (kk == 1024)    v = *(const float4*)(Wih + (size_t)sr * 516 + 512);
    else                    zero = true;
  } else if (k < KG1) {                 // ctx: lo then hi
    lo = (k < 2624);
    const int kk = lo ? k - 2112 : k - 2624;
    v = *(const float4*)(Wih + (size_t)sr * 516 + kk);
  } else if (k < 4192) {                // h-block hi (dup)
    lo = false;
    const int kk = k - KG1;
    if (kk < 1024)          v = *(const float4*)(Whh + (size_t)sr * HDIM + kk);
    else if (kk == 1024)    v = *(const float4*)(Wih + (size_t)sr * 516 + 512);
    else                    zero = true;
  } else {                              // ctx hi (dup)
    lo = false;
    v = *(const float4*)(Wih + (size_t)sr * 516 + (k - 4192));
  }
  half_t* d = dst + (size_t)rp * KGT + k;
  if (zero)      { halfx4 z = {0,0,0,0}; *(halfx4*)d = z; }
  else if (lo)   { halfx4 o = { lo16(v.x), lo16(v.y), lo16(v.z), lo16(v.w) }; *(halfx4*)d = o; }
  else           { halfx4 o = { hi16(v.x), hi16(v.y), hi16(v.z), hi16(v.w) }; *(halfx4*)d = o; }
}

// bias_i[r'] = b_ih[src] + b_hh[src]
__global__ __launch_bounds__(256)
void build_bias(const float* __restrict__ b_ih, const float* __restrict__ b_hh,
                float* __restrict__ bias_i) {
  int rp = blockIdx.x * 256 + threadIdx.x;
  if (rp >= GDIM) return;
  const int sr = (rp & 3) * HDIM + (rp >> 2);
  bias_i[rp] = b_ih[sr] + b_hh[sr];
}

// W1g_cat [1024][3072] = [lo_s | hi | hi] of W1*ln_g; v1=W1g·1; v2=W1·beta+b1
__global__ __launch_bounds__(256)
void build_w1g_cat(const float* __restrict__ W1, const float* __restrict__ g,
                   const float* __restrict__ beta, const float* __restrict__ b1,
                   half_t* __restrict__ W1g, float* __restrict__ v1,
                   float* __restrict__ v2) {
  const int n = blockIdx.x;
  const int tid = threadIdx.x;
  const int k = tid * 4;
  const float4 w  = *(const float4*)(W1 + (size_t)n * HDIM + k);
  const float4 gg = *(const float4*)(g + k);
  const float4 bb = *(const float4*)(beta + k);
  const float wg0 = w.x*gg.x, wg1 = w.y*gg.y, wg2 = w.z*gg.z, wg3 = w.w*gg.w;
  halfx4 hl = { lo16(wg0), lo16(wg1), lo16(wg2), lo16(wg3) };
  halfx4 hh = { hi16(wg0), hi16(wg1), hi16(wg2), hi16(wg3) };
  *(halfx4*)(W1g + (size_t)n * 3072 + k)        = hl;
  *(halfx4*)(W1g + (size_t)n * 3072 + 1024 + k) = hh;
  *(halfx4*)(W1g + (size_t)n * 3072 + 2048 + k) = hh;
  float s1 = wg0 + wg1 + wg2 + wg3;
  float s2 = w.x*bb.x + w.y*bb.y + w.z*bb.z + w.w*bb.w;
#pragma unroll
  for (int off = 32; off > 0; off >>= 1) {
    s1 += __shfl_down(s1, off, 64);
    s2 += __shfl_down(s2, off, 64);
  }
  __shared__ float t1[4], t2[4];
  const int wv = tid >> 6, ln = tid & 63;
  if (ln == 0) { t1[wv] = s1; t2[wv] = s2; }
  __syncthreads();
  if (tid == 0) {
    v1[n] = t1[0] + t1[1] + t1[2] + t1[3];
    v2[n] = t2[0] + t2[1] + t2[2] + t2[3] + b1[n];
  }
}

// Wc_cat [1024][1536] = [lo_s | hi | hi] of a [1024][512] fp32 matrix
__global__ __launch_bounds__(128)
void build_wc_cat(const float* __restrict__ W, half_t* __restrict__ dst) {
  const int n = blockIdx.x;
  const int k = threadIdx.x * 4;
  const float4 w = *(const float4*)(W + (size_t)n * CDIM + k);
  halfx4 hl = { lo16(w.x), lo16(w.y), lo16(w.z), lo16(w.w) };
  halfx4 hh = { hi16(w.x), hi16(w.y), hi16(w.z), hi16(w.w) };
  *(halfx4*)(dst + (size_t)n * 1536 + k)        = hl;
  *(halfx4*)(dst + (size_t)n * 1536 + 512 + k)  = hh;
  *(halfx4*)(dst + (size_t)n * 1536 + 1024 + k) = hh;
}

__global__ __launch_bounds__(256)
void init_chunk(const float* __restrict__ lp, const float* __restrict__ ld,
                float* __restrict__ pos, half_t* __restrict__ h0hi,
                half_t* __restrict__ h0lo, half_t* __restrict__ h1hi,
                half_t* __restrict__ h1lo, int M) {
  int b = blockIdx.x * 256 + threadIdx.x;
  if (b >= M) return;
  pos[2*b]   = lp[2*b];
  pos[2*b+1] = lp[2*b+1];
  const float dx = ld[2*b], dy = ld[2*b+1];
  const float nrm = fmaxf(sqrtf(dx*dx + dy*dy), 1e-6f);
  const float hx = dx / nrm, hy = dy / nrm;
  const size_t base = (size_t)b * HEXT + HDIM;
  // zero all pad+extra cols of both ping-pong buffers (hi & lo)
#pragma unroll
  for (int k = 0; k < 32; k += 4) {
    halfx4 z = {0,0,0,0};
    *(halfx4*)(h0hi + base + k) = z;
    *(halfx4*)(h0lo + base + k) = z;
    *(halfx4*)(h1hi + base + k) = z;
    *(halfx4*)(h1lo + base + k) = z;
  }
  halfx4 ehi = { hi16(dx), hi16(dy), hi16(hx), hi16(hy) };
  halfx4 elo = { lo16(dx), lo16(dy), lo16(hx), lo16(hy) };
  *(halfx4*)(h0hi + base) = ehi;
  *(halfx4*)(h0lo + base) = elo;
}

extern "C" void kernel_launch(void* const* d_in, const int* in_sizes, int n_in,
                              void* d_out, int out_size, void* d_ws, size_t ws_size,
                              hipStream_t stream) {
  const float* context    = (const float*)d_in[0];
  const float* last_pos   = (const float*)d_in[1];
  const float* last_delta = (const float*)d_in[2];
  const float* Wh   = (const float*)d_in[3];
  const float* bh   = (const float*)d_in[4];
  const float* Wc   = (const float*)d_in[5];
  const float* bc   = (const float*)d_in[6];
  const float* W_ih = (const float*)d_in[7];
  const float* b_ih = (const float*)d_in[8];
  const float* W_hh = (const float*)d_in[9];
  const float* b_hh = (const float*)d_in[10];
  const float* ln_g = (const float*)d_in[11];
  const float* ln_b = (const float*)d_in[12];
  const float* W1   = (const float*)d_in[13];
  const float* b1   = (const float*)d_in[14];
  const float* W2   = (const float*)d_in[15];
  const float* b2   = (const float*)d_in[16];
  float* out = (float*)d_out;

  // ---- workspace plan: static weights + per-chunk state (batch in NC chunks)
  const size_t stat_bytes =
      (size_t)GDIM * KGT * 2 + (size_t)HDIM * 3072 * 2 +
      2 * (size_t)HDIM * 1536 * 2 + (size_t)GDIM * 4 + 2 * (size_t)HDIM * 4 + 8192;
  int NC = 0;
  for (int nc : {1, 2, 4, 8}) {
    const size_t M = BATCH / nc;
    const size_t chunk_bytes = 4 * M * HEXT * 2 + 2 * M * CDIM * 2 +
                               M * HDIM * 4 + 3 * M * 2 * 4 + 8192;
    if (stat_bytes + chunk_bytes <= ws_size) { NC = nc; break; }
  }
  if (NC == 0) return;   // ws too small: stub-identical absmax = diagnostic
  const int M = BATCH / NC;

  char* w = (char*)d_ws;
  auto take = [&](size_t bytes) {
    char* p = w;
    w += (bytes + 255) & ~(size_t)255;
    return p;
  };
  half_t* Whh_cat = (half_t*)take((size_t)GDIM * KGT * 2);
  half_t* W1g_cat = (half_t*)take((size_t)HDIM * 3072 * 2);
  half_t* Wh_cat  = (half_t*)take((size_t)HDIM * 1536 * 2);
  half_t* Wc_cat  = (half_t*)take((size_t)HDIM * 1536 * 2);
  float*  bias_i  = (float*)take((size_t)GDIM * 4);
  float*  v1      = (float*)take((size_t)HDIM * 4);
  float*  v2      = (float*)take((size_t)HDIM * 4);
  half_t* h0hi    = (half_t*)take((size_t)M * HEXT * 2);
  half_t* h0lo    = (half_t*)take((size_t)M * HEXT * 2);
  half_t* h1hi    = (half_t*)take((size_t)M * HEXT * 2);
  half_t* h1lo    = (half_t*)take((size_t)M * HEXT * 2);
  half_t* ctx_hi  = (half_t*)take((size_t)M * CDIM * 2);
  half_t* ctx_lo  = (half_t*)take((size_t)M * CDIM * 2);
  float*  c_f     = (float*)take((size_t)M * HDIM * 4);
  float*  stats   = (float*)take((size_t)M * 2 * 4);
  float*  pos_f   = (float*)take((size_t)M * 2 * 4);
  float*  delta   = (float*)take((size_t)M * 2 * 4);

  // static builders (once)
  build_whh_cat<<<(GDIM * (KGT/4) + 255) / 256, 256, 0, stream>>>(W_hh, W_ih, Whh_cat);
  build_bias<<<(GDIM + 255) / 256, 256, 0, stream>>>(b_ih, b_hh, bias_i);
  build_w1g_cat<<<HDIM, 256, 0, stream>>>(W1, ln_g, ln_b, b1, W1g_cat, v1, v2);
  build_wc_cat<<<HDIM, 128, 0, stream>>>(Wh, Wh_cat);
  build_wc_cat<<<HDIM, 128, 0, stream>>>(Wc, Wc_cat);

  const dim3 blk(256);
  for (int chunk = 0; chunk < NC; ++chunk) {
    const size_t base = (size_t)chunk * M;
    cvt_split<<<(M * CDIM / 4 + 255) / 256, 256, 0, stream>>>(
        context + base * CDIM, ctx_hi, ctx_lo, M * CDIM / 4);
    // h0 = tanh(ctx @ Wh^T + bh) split-fp16; c0 = tanh(ctx @ Wc^T + bc) fp32
    gemm3_pre<true ><<<dim3(M/128, HDIM/128), blk, 0, stream>>>(
        ctx_hi, ctx_lo, Wh_cat, bh, nullptr, h0hi, h0lo);
    gemm3_pre<false><<<dim3(M/128, HDIM/128), blk, 0, stream>>>(
        ctx_hi, ctx_lo, Wc_cat, bc, c_f, nullptr, nullptr);
    init_chunk<<<(M + 255) / 256, 256, 0, stream>>>(
        last_pos + base * 2, last_delta + base * 2, pos_f, h0hi, h0lo, h1hi, h1lo, M);

    const half_t* hAhi = h0hi; const half_t* hAlo = h0lo;
    half_t* hBhi = h1hi; half_t* hBlo = h1lo;
    for (int t = 0; t < TSTEP; ++t) {
      gemm_gates_cell<<<dim3(M/128, GDIM/128), blk, 0, stream>>>(
          hAhi, hAlo, ctx_hi, ctx_lo, Whh_cat, bias_i, c_f, hBhi, hBlo);
      ln_stats<<<M, 256, 0, stream>>>(hBhi, hBlo, stats, delta);
      gemm_mlp<<<dim3(M/128, HDIM/128), blk, 0, stream>>>(
          hBhi, hBlo, W1g_cat, stats, v1, v2, W2, delta);
      finalize_step<<<(M + 255) / 256, 256, 0, stream>>>(
          delta, b2, pos_f, out + base * TSTEP * 2, hBhi, hBlo, t, M);
      half_t* th = hBhi; hBhi = (half_t*)hAhi; hAhi = th;
      half_t* tl = hBlo; hBlo = (half_t*)hAlo; hAlo = tl;
    }
  }
  (void)in_sizes; (void)n_in; (void)out_size;
}

// Round 7
// 58542.004 us; speedup vs baseline: 1.0531x; 1.0531x over previous
//
#include <hip/hip_runtime.h>
#include <math.h>

constexpr int BATCH = 16384;
constexpr int CDIM  = 512;
constexpr int HDIM  = 1024;
constexpr int GDIM  = 4096;   // 4*H
constexpr int HEXT  = 1056;   // HDIM + 4 extra + 28 zero-pad (mult of 32)
constexpr int TSTEP = 60;
// gates GEMM K layout (split-fp16, h-recurrence only; ctx precomputed in gctx):
//   phase1 [0,2112):    [W_lo(h,pre-scaled 2^11) x h_hi | W_hi(h) x h_lo(pre-scaled)]
//   (acc *= 2^-11)
//   phase2 [2112,3168): W_hi(h) x h_hi
constexpr int KG1 = 2112;
constexpr int KGT = 3168;
constexpr float LOSC  = 2048.0f;       // 2^11
constexpr float ILOSC = 1.0f / 2048.0f;

typedef _Float16 half_t;
typedef _Float16 halfx8 __attribute__((ext_vector_type(8)));
typedef _Float16 halfx4 __attribute__((ext_vector_type(4)));
typedef float    f32x4  __attribute__((ext_vector_type(4)));

__device__ __forceinline__ void async_cp16(const void* g, void* l) {
  __builtin_amdgcn_global_load_lds((__attribute__((address_space(1))) void*)g,
                                   (__attribute__((address_space(3))) void*)l,
                                   16, 0, 0);
}

__device__ __forceinline__ half_t hi16(float x) { return (half_t)x; }
__device__ __forceinline__ half_t lo16(float x) {    // pre-scaled residual
  return (half_t)((x - (float)((half_t)x)) * LOSC);
}
__device__ __forceinline__ float sigf(float x) { return 1.0f / (1.0f + expf(-x)); }
__device__ __forceinline__ float geluf(float v) {
  return 0.5f * v * (1.0f + erff(v * 0.70710678118f));
}

// ---------- one BK=32 step of the m97 GEMM core ----------
__device__ __forceinline__ void kstep(f32x4 (&acc)[4][4],
    const half_t* __restrict__ A, size_t lda, int krel,
    const half_t* __restrict__ W, size_t ldw, int kw,
    half_t* sA, half_t* sB, int bm0, int bn0) {
  const int tid  = threadIdx.x;
  const int lane = tid & 63;
  const int wave = tid >> 6;
  const int wm = wave >> 1, wn = wave & 1;
  const int ar = lane >> 2;
  const int ak = (lane & 3) * 8;
  const int quad = lane >> 4;
  const int lcol = lane & 15;
#pragma unroll
  for (int cc = 0; cc < 2; ++cc) {
    const int chunk = wave + cc * 4;
    async_cp16(A + (size_t)(bm0 + chunk * 16 + ar) * lda + (krel + ak), sA + chunk * 512);
    async_cp16(W + (size_t)(bn0 + chunk * 16 + ar) * ldw + (kw + ak), sB + chunk * 512);
  }
  asm volatile("s_waitcnt vmcnt(0)" ::: "memory");
  __syncthreads();
  halfx8 af[4], bfr[4];
#pragma unroll
  for (int mi = 0; mi < 4; ++mi)
    af[mi] = *(const halfx8*)&sA[(wm * 64 + mi * 16 + lcol) * 32 + quad * 8];
#pragma unroll
  for (int ni = 0; ni < 4; ++ni)
    bfr[ni] = *(const halfx8*)&sB[(wn * 64 + ni * 16 + lcol) * 32 + quad * 8];
#pragma unroll
  for (int mi = 0; mi < 4; ++mi)
#pragma unroll
    for (int ni = 0; ni < 4; ++ni)
      acc[mi][ni] = __builtin_amdgcn_mfma_f32_16x16x32_f16(af[mi], bfr[ni], acc[mi][ni], 0, 0, 0);
  __syncthreads();
}

__device__ __forceinline__ void scale_acc(f32x4 (&acc)[4][4], float s) {
#pragma unroll
  for (int i = 0; i < 4; ++i)
#pragma unroll
    for (int j = 0; j < 4; ++j) acc[i][j] *= s;
}

// ---------- preamble split GEMM (K=1536: [W_lo x A_hi | W_hi x A_lo | W_hi x A_hi])
// ACT: 0=none 1=tanh.  SPLITOUT: write hi/lo fp16 pair (ldc=HEXT) else fp32 (ldc param)
template <int ACT, bool SPLITOUT>
__global__ __launch_bounds__(256, 2)
void gemm3_pre(const half_t* __restrict__ Ahi, const half_t* __restrict__ Alo,
               const half_t* __restrict__ Wcat, const float* __restrict__ bias,
               float* __restrict__ Cf, half_t* __restrict__ Chi,
               half_t* __restrict__ Clo, int ldc) {
  __shared__ __align__(16) half_t sA[128 * 32];
  __shared__ __align__(16) half_t sB[128 * 32];
  const int tid = threadIdx.x;
  const int bm0 = blockIdx.x * 128, bn0 = blockIdx.y * 128;
  f32x4 acc[4][4];
#pragma unroll
  for (int i = 0; i < 4; ++i)
#pragma unroll
    for (int j = 0; j < 4; ++j) acc[i][j] = (f32x4){0.f, 0.f, 0.f, 0.f};
#pragma unroll 1
  for (int k0 = 0; k0 < 1024; k0 += 32) {
    const half_t* A = (k0 < 512) ? Ahi : Alo;
    kstep(acc, A, CDIM, k0 & 511, Wcat, 1536, k0, sA, sB, bm0, bn0);
  }
  scale_acc(acc, ILOSC);
#pragma unroll 1
  for (int k0 = 1024; k0 < 1536; k0 += 32)
    kstep(acc, Ahi, CDIM, k0 - 1024, Wcat, 1536, k0, sA, sB, bm0, bn0);

  const int lane = tid & 63, wave = tid >> 6;
  const int wm = wave >> 1, wn = wave & 1, quad = lane >> 4, lcol = lane & 15;
#pragma unroll
  for (int ni = 0; ni < 4; ++ni) {
    const int col = bn0 + wn * 64 + ni * 16 + lcol;
    const float bv = bias[col];
#pragma unroll
    for (int mi = 0; mi < 4; ++mi) {
      const int row0 = bm0 + wm * 64 + mi * 16 + quad * 4;
#pragma unroll
      for (int r = 0; r < 4; ++r) {
        float v = acc[mi][ni][r] + bv;
        if (ACT == 1) v = tanhf(v);
        if (SPLITOUT) {
          const size_t idx = (size_t)(row0 + r) * HEXT + col;
          Chi[idx] = hi16(v);
          Clo[idx] = lo16(v);
        } else {
          Cf[(size_t)(row0 + r) * ldc + col] = v;
        }
      }
    }
  }
}

// ---------- fused gates GEMM (split-K 3168, h-only) + LSTM cell + LN-stats ----------
// gctx holds ctx@Wihc^T + b_ih + b_hh (fp32, interleaved cols r'=4u+g).
// Epilogue: LDS transpose (stride 68: 2-way conflicts = free), gather 4 gates,
// LSTM update (c fp32), h -> split fp16 pair, accumulate LN sum/sumsq atomics.
__global__ __launch_bounds__(256, 2)
void gemm_gates_cell(const half_t* __restrict__ hAhi, const half_t* __restrict__ hAlo,
                     const half_t* __restrict__ Whh, const float* __restrict__ gctx,
                     float* __restrict__ c, half_t* __restrict__ hBhi,
                     half_t* __restrict__ hBlo, float* __restrict__ stats) {
  __shared__ __align__(16) half_t sA[128 * 32];
  __shared__ __align__(16) half_t sB[128 * 32];
  __shared__ __align__(16) float sE[4][16 * 68];
  const int tid = threadIdx.x;
  const int bm0 = blockIdx.x * 128, bn0 = blockIdx.y * 128;
  f32x4 acc[4][4];
#pragma unroll
  for (int i = 0; i < 4; ++i)
#pragma unroll
    for (int j = 0; j < 4; ++j) acc[i][j] = (f32x4){0.f, 0.f, 0.f, 0.f};

#pragma unroll 1
  for (int k0 = 0; k0 < KG1; k0 += 32) {
    const half_t* A = (k0 < 1056) ? hAhi : hAlo;
    const int krel = (k0 < 1056) ? k0 : k0 - 1056;
    kstep(acc, A, HEXT, krel, Whh, KGT, k0, sA, sB, bm0, bn0);
  }
  scale_acc(acc, ILOSC);
#pragma unroll 1
  for (int k0 = KG1; k0 < KGT; k0 += 32)
    kstep(acc, hAhi, HEXT, k0 - KG1, Whh, KGT, k0, sA, sB, bm0, bn0);

  const int lane = tid & 63, wave = tid >> 6;
  const int wm = wave >> 1, wn = wave & 1, quad = lane >> 4, lcol = lane & 15;
  float* myE = sE[wave];
  const int u = lane & 15;
  const int q = lane >> 4;
  const int jbase = (bn0 + wn * 64) >> 2;

#pragma unroll
  for (int mi = 0; mi < 4; ++mi) {
#pragma unroll
    for (int ni = 0; ni < 4; ++ni)
#pragma unroll
      for (int r = 0; r < 4; ++r)
        myE[(quad * 4 + r) * 68 + ni * 16 + lcol] = acc[mi][ni][r];
    // same-wave DS ops are in-order: reads below see the writes above
#pragma unroll
    for (int k = 0; k < 4; ++k) {
      const int rr = q + 4 * k;
      const int row = bm0 + wm * 64 + mi * 16 + rr;
      const f32x4 gv = *(const f32x4*)&myE[rr * 68 + u * 4];  // {i,f,g,o} h-part
      const int j = jbase + u;
      const float4 gc = *(const float4*)(gctx + (size_t)row * GDIM + 4 * j);
      const float pi = gv[0] + gc.x;
      const float pf = gv[1] + gc.y;
      const float pg = gv[2] + gc.z;
      const float po = gv[3] + gc.w;
      const size_t cidx = (size_t)row * HDIM + j;
      const float cn = sigf(pf) * c[cidx] + sigf(pi) * tanhf(pg);
      c[cidx] = cn;
      const float vh = sigf(po) * tanhf(cn);
      const size_t hidx = (size_t)row * HEXT + j;
      hBhi[hidx] = hi16(vh);
      hBlo[hidx] = lo16(vh);
      // LN stats partial over this wave's 16 units of this row
      float ps = vh, pq = vh * vh;
#pragma unroll
      for (int m = 1; m < 16; m <<= 1) {
        ps += __shfl_xor(ps, m, 64);
        pq += __shfl_xor(pq, m, 64);
      }
      if (u == 0) {
        atomicAdd(&stats[2 * row], ps);
        atomicAdd(&stats[2 * row + 1], pq);
      }
    }
  }
}

// ---------- MLP GEMM (split-K 3072): LN folded, gelu + W2-dot fused ----------
// delta errors feed back into the recurrence via extra(t+1) -> must stay
// at 22-bit split precision (round-6 fp16 regression: absmax 0.5 -> 4.03).
__global__ __launch_bounds__(256, 2)
void gemm_mlp(const half_t* __restrict__ hBhi, const half_t* __restrict__ hBlo,
              const half_t* __restrict__ W1g, const float* __restrict__ stats,
              const float* __restrict__ v1, const float* __restrict__ v2,
              const float* __restrict__ W2, float* __restrict__ delta) {
  __shared__ __align__(16) half_t sA[128 * 32];
  __shared__ __align__(16) half_t sB[128 * 32];
  const int tid = threadIdx.x;
  const int bm0 = blockIdx.x * 128, bn0 = blockIdx.y * 128;
  f32x4 acc[4][4];
#pragma unroll
  for (int i = 0; i < 4; ++i)
#pragma unroll
    for (int j = 0; j < 4; ++j) acc[i][j] = (f32x4){0.f, 0.f, 0.f, 0.f};
#pragma unroll 1
  for (int k0 = 0; k0 < 2048; k0 += 32) {
    const half_t* A = (k0 < 1024) ? hBhi : hBlo;
    kstep(acc, A, HEXT, k0 & 1023, W1g, 3072, k0, sA, sB, bm0, bn0);
  }
  scale_acc(acc, ILOSC);
#pragma unroll 1
  for (int k0 = 2048; k0 < 3072; k0 += 32)
    kstep(acc, hBhi, HEXT, k0 - 2048, W1g, 3072, k0, sA, sB, bm0, bn0);

  const int lane = tid & 63, wave = tid >> 6;
  const int wm = wave >> 1, wn = wave & 1, quad = lane >> 4, lcol = lane & 15;
  float w2a[4], w2b[4], v1c[4], v2c[4];
#pragma unroll
  for (int ni = 0; ni < 4; ++ni) {
    const int col = bn0 + wn * 64 + ni * 16 + lcol;
    w2a[ni] = W2[col]; w2b[ni] = W2[HDIM + col];
    v1c[ni] = v1[col]; v2c[ni] = v2[col];
  }
#pragma unroll
  for (int mi = 0; mi < 4; ++mi) {
#pragma unroll
    for (int r = 0; r < 4; ++r) {
      const int row = bm0 + wm * 64 + mi * 16 + quad * 4 + r;
      const float S = stats[2 * row], Q = stats[2 * row + 1];
      const float mu = S * (1.0f / HDIM);
      const float rs = rsqrtf(Q * (1.0f / HDIM) - mu * mu + 1e-5f);
      float d0 = 0.f, d1 = 0.f;
#pragma unroll
      for (int ni = 0; ni < 4; ++ni) {
        const float g = geluf(rs * (acc[mi][ni][r] - mu * v1c[ni]) + v2c[ni]);
        d0 += g * w2a[ni];
        d1 += g * w2b[ni];
      }
#pragma unroll
      for (int m = 1; m < 16; m <<= 1) {
        d0 += __shfl_xor(d0, m, 64);
        d1 += __shfl_xor(d1, m, 64);
      }
      if (lcol == 0) {
        atomicAdd(&delta[2 * row], d0);
        atomicAdd(&delta[2 * row + 1], d1);
      }
    }
  }
}

// ---------- pos update + out write + next-step extra + zero stats/delta ----------
__global__ __launch_bounds__(256)
void finalize_step(const float* __restrict__ delta_in, const float* __restrict__ b2,
                   float* __restrict__ pos, float* __restrict__ out,
                   half_t* __restrict__ hNhi, half_t* __restrict__ hNlo,
                   float* __restrict__ stats, float* __restrict__ delta,
                   int t, int M) {
  const int b = blockIdx.x * 256 + threadIdx.x;
  if (b >= M) return;
  const float dx = delta_in[2*b]   + b2[0];
  const float dy = delta_in[2*b+1] + b2[1];
  const float px = pos[2*b] + dx, py = pos[2*b+1] + dy;
  pos[2*b] = px; pos[2*b+1] = py;
  out[((size_t)b * TSTEP + t) * 2 + 0] = px;
  out[((size_t)b * TSTEP + t) * 2 + 1] = py;
  const float nrm = fmaxf(sqrtf(dx*dx + dy*dy), 1e-6f);
  const float hx = dx / nrm, hy = dy / nrm;
  const size_t e = (size_t)b * HEXT + HDIM;
  halfx4 ehi = { hi16(dx), hi16(dy), hi16(hx), hi16(hy) };
  halfx4 elo = { lo16(dx), lo16(dy), lo16(hx), lo16(hy) };
  *(halfx4*)(hNhi + e) = ehi;
  *(halfx4*)(hNlo + e) = elo;
  stats[2*b] = 0.f; stats[2*b+1] = 0.f;
  delta[2*b] = 0.f; delta[2*b+1] = 0.f;
}

// ---------- builders ----------
__global__ __launch_bounds__(256)
void cvt_split(const float* __restrict__ s, half_t* __restrict__ dhi,
               half_t* __restrict__ dlo, int n4) {
  int i = blockIdx.x * 256 + threadIdx.x;
  if (i >= n4) return;
  const float4 v = ((const float4*)s)[i];
  halfx4 h = { hi16(v.x), hi16(v.y), hi16(v.z), hi16(v.w) };
  halfx4 l = { lo16(v.x), lo16(v.y), lo16(v.z), lo16(v.w) };
  *(halfx4*)(dhi + (size_t)i * 4) = h;
  *(halfx4*)(dlo + (size_t)i * 4) = l;
}

// Whh_cat [4096][3168]: rows r'=4u+g (src sr=(rp&3)*H+(rp>>2)); h-block source:
// kk<1024 -> W_hh[sr][kk]; kk==1024..1027 -> W_ih[sr][512+...]; else 0.
// cols: [0,1056)=lo(pre-scaled), [1056,2112)=hi, [2112,3168)=hi dup
__global__ __launch_bounds__(256)
void build_whh_cat(const float* __restrict__ Whh, const float* __restrict__ Wih,
                   half_t* __restrict__ dst) {
  int idx = blockIdx.x * 256 + threadIdx.x;
  if (idx >= GDIM * (KGT / 4)) return;
  const int rp = idx / (KGT / 4);
  const int k  = (idx - rp * (KGT / 4)) * 4;
  const int sr = (rp & 3) * HDIM + (rp >> 2);
  const bool lo = (k < 1056);
  const int kk = lo ? k : (k < KG1 ? k - 1056 : k - KG1);
  float4 v; bool zero = false;
  if (kk < 1024)       v = *(const float4*)(Whh + (size_t)sr * HDIM + kk);
  else if (kk == 1024) v = *(const float4*)(Wih + (size_t)sr * 516 + 512);
  else                 zero = true;
  half_t* d = dst + (size_t)rp * KGT + k;
  if (zero)    { halfx4 z = {0,0,0,0}; *(halfx4*)d = z; }
  else if (lo) { halfx4 o = { lo16(v.x), lo16(v.y), lo16(v.z), lo16(v.w) }; *(halfx4*)d = o; }
  else         { halfx4 o = { hi16(v.x), hi16(v.y), hi16(v.z), hi16(v.w) }; *(halfx4*)d = o; }
}

// Wih_cat [4096][1536] = [lo_s | hi | hi] of W_ih[:, :512], rows interleaved
__global__ __launch_bounds__(256)
void build_wih_cat(const float* __restrict__ Wih, half_t* __restrict__ dst) {
  int idx = blockIdx.x * 256 + threadIdx.x;
  if (idx >= GDIM * 384) return;
  const int rp = idx / 384;
  const int k  = (idx - rp * 384) * 4;
  const int sr = (rp & 3) * HDIM + (rp >> 2);
  const bool lo = (k < 512);
  const int kk = lo ? k : (k < 1024 ? k - 512 : k - 1024);
  const float4 v = *(const float4*)(Wih + (size_t)sr * 516 + kk);
  half_t* d = dst + (size_t)rp * 1536 + k;
  if (lo) { halfx4 o = { lo16(v.x), lo16(v.y), lo16(v.z), lo16(v.w) }; *(halfx4*)d = o; }
  else    { halfx4 o = { hi16(v.x), hi16(v.y), hi16(v.z), hi16(v.w) }; *(halfx4*)d = o; }
}

// bias_i[r'] = b_ih[src] + b_hh[src]
__global__ __launch_bounds__(256)
void build_bias(const float* __restrict__ b_ih, const float* __restrict__ b_hh,
                float* __restrict__ bias_i) {
  int rp = blockIdx.x * 256 + threadIdx.x;
  if (rp >= GDIM) return;
  const int sr = (rp & 3) * HDIM + (rp >> 2);
  bias_i[rp] = b_ih[sr] + b_hh[sr];
}

// W1g_cat [1024][3072] = [lo_s | hi | hi] of W1*ln_g; v1=W1g·1; v2=W1·beta + b1
__global__ __launch_bounds__(256)
void build_w1g_cat(const float* __restrict__ W1, const float* __restrict__ g,
                   const float* __restrict__ beta, const float* __restrict__ b1,
                   half_t* __restrict__ W1g, float* __restrict__ v1,
                   float* __restrict__ v2) {
  const int n = blockIdx.x;
  const int tid = threadIdx.x;
  const int k = tid * 4;
  const float4 w  = *(const float4*)(W1 + (size_t)n * HDIM + k);
  const float4 gg = *(const float4*)(g + k);
  const float4 bb = *(const float4*)(beta + k);
  const float wg0 = w.x*gg.x, wg1 = w.y*gg.y, wg2 = w.z*gg.z, wg3 = w.w*gg.w;
  halfx4 hl = { lo16(wg0), lo16(wg1), lo16(wg2), lo16(wg3) };
  halfx4 hh = { hi16(wg0), hi16(wg1), hi16(wg2), hi16(wg3) };
  *(halfx4*)(W1g + (size_t)n * 3072 + k)        = hl;
  *(halfx4*)(W1g + (size_t)n * 3072 + 1024 + k) = hh;
  *(halfx4*)(W1g + (size_t)n * 3072 + 2048 + k) = hh;
  float s1 = wg0 + wg1 + wg2 + wg3;
  float s2 = w.x*bb.x + w.y*bb.y + w.z*bb.z + w.w*bb.w;
#pragma unroll
  for (int off = 32; off > 0; off >>= 1) {
    s1 += __shfl_down(s1, off, 64);
    s2 += __shfl_down(s2, off, 64);
  }
  __shared__ float t1[4], t2[4];
  const int wv = tid >> 6, ln = tid & 63;
  if (ln == 0) { t1[wv] = s1; t2[wv] = s2; }
  __syncthreads();
  if (tid == 0) {
    v1[n] = t1[0] + t1[1] + t1[2] + t1[3];
    v2[n] = t2[0] + t2[1] + t2[2] + t2[3] + b1[n];
  }
}

// Wc_cat [1024][1536] = [lo_s | hi | hi] of a [1024][512] fp32 matrix
__global__ __launch_bounds__(128)
void build_wc_cat(const float* __restrict__ W, half_t* __restrict__ dst) {
  const int n = blockIdx.x;
  const int k = threadIdx.x * 4;
  const float4 w = *(const float4*)(W + (size_t)n * CDIM + k);
  halfx4 hl = { lo16(w.x), lo16(w.y), lo16(w.z), lo16(w.w) };
  halfx4 hh = { hi16(w.x), hi16(w.y), hi16(w.z), hi16(w.w) };
  *(halfx4*)(dst + (size_t)n * 1536 + k)        = hl;
  *(halfx4*)(dst + (size_t)n * 1536 + 512 + k)  = hh;
  *(halfx4*)(dst + (size_t)n * 1536 + 1024 + k) = hh;
}

__global__ __launch_bounds__(256)
void init_chunk(const float* __restrict__ lp, const float* __restrict__ ld,
                float* __restrict__ pos, half_t* __restrict__ h0hi,
                half_t* __restrict__ h0lo, half_t* __restrict__ h1hi,
                half_t* __restrict__ h1lo, float* __restrict__ stats,
                float* __restrict__ delta, int M) {
  int b = blockIdx.x * 256 + threadIdx.x;
  if (b >= M) return;
  pos[2*b]   = lp[2*b];
  pos[2*b+1] = lp[2*b+1];
  stats[2*b] = 0.f; stats[2*b+1] = 0.f;
  delta[2*b] = 0.f; delta[2*b+1] = 0.f;
  const float dx = ld[2*b], dy = ld[2*b+1];
  const float nrm = fmaxf(sqrtf(dx*dx + dy*dy), 1e-6f);
  const float hx = dx / nrm, hy = dy / nrm;
  const size_t base = (size_t)b * HEXT + HDIM;
#pragma unroll
  for (int k = 0; k < 32; k += 4) {
    halfx4 z = {0,0,0,0};
    *(halfx4*)(h0hi + base + k) = z;
    *(halfx4*)(h0lo + base + k) = z;
    *(halfx4*)(h1hi + base + k) = z;
    *(halfx4*)(h1lo + base + k) = z;
  }
  halfx4 ehi = { hi16(dx), hi16(dy), hi16(hx), hi16(hy) };
  halfx4 elo = { lo16(dx), lo16(dy), lo16(hx), lo16(hy) };
  *(halfx4*)(h0hi + base) = ehi;
  *(halfx4*)(h0lo + base) = elo;
}

extern "C" void kernel_launch(void* const* d_in, const int* in_sizes, int n_in,
                              void* d_out, int out_size, void* d_ws, size_t ws_size,
                              hipStream_t stream) {
  const float* context    = (const float*)d_in[0];
  const float* last_pos   = (const float*)d_in[1];
  const float* last_delta = (const float*)d_in[2];
  const float* Wh   = (const float*)d_in[3];
  const float* bh   = (const float*)d_in[4];
  const float* Wc   = (const float*)d_in[5];
  const float* bc   = (const float*)d_in[6];
  const float* W_ih = (const float*)d_in[7];
  const float* b_ih = (const float*)d_in[8];
  const float* W_hh = (const float*)d_in[9];
  const float* b_hh = (const float*)d_in[10];
  const float* ln_g = (const float*)d_in[11];
  const float* ln_b = (const float*)d_in[12];
  const float* W1   = (const float*)d_in[13];
  const float* b1   = (const float*)d_in[14];
  const float* W2   = (const float*)d_in[15];
  const float* b2   = (const float*)d_in[16];
  float* out = (float*)d_out;

  // ---- workspace plan: static weights + per-chunk state (batch in NC chunks)
  const size_t stat_bytes =
      (size_t)GDIM * KGT * 2 + (size_t)GDIM * 1536 * 2 + (size_t)HDIM * 3072 * 2 +
      2 * (size_t)HDIM * 1536 * 2 + (size_t)GDIM * 4 + 2 * (size_t)HDIM * 4 + 16384;
  int NC = 0;
  for (int nc : {2, 4, 8, 16}) {
    const size_t M = BATCH / nc;
    const size_t chunk_bytes = 4 * M * HEXT * 2 + 2 * M * CDIM * 2 +
                               M * HDIM * 4 + (size_t)M * GDIM * 4 +
                               3 * M * 2 * 4 + 16384;
    if (stat_bytes + chunk_bytes <= ws_size) { NC = nc; break; }
  }
  if (NC == 0) return;   // ws too small: stub-identical absmax = diagnostic
  const int M = BATCH / NC;

  char* w = (char*)d_ws;
  auto take = [&](size_t bytes) {
    char* p = w;
    w += (bytes + 255) & ~(size_t)255;
    return p;
  };
  half_t* Whh_cat = (half_t*)take((size_t)GDIM * KGT * 2);
  half_t* Wih_cat = (half_t*)take((size_t)GDIM * 1536 * 2);
  half_t* W1g_cat = (half_t*)take((size_t)HDIM * 3072 * 2);
  half_t* Wh_cat  = (half_t*)take((size_t)HDIM * 1536 * 2);
  half_t* Wc_cat  = (half_t*)take((size_t)HDIM * 1536 * 2);
  float*  bias_i  = (float*)take((size_t)GDIM * 4);
  float*  v1      = (float*)take((size_t)HDIM * 4);
  float*  v2      = (float*)take((size_t)HDIM * 4);
  half_t* h0hi    = (half_t*)take((size_t)M * HEXT * 2);
  half_t* h0lo    = (half_t*)take((size_t)M * HEXT * 2);
  half_t* h1hi    = (half_t*)take((size_t)M * HEXT * 2);
  half_t* h1lo    = (half_t*)take((size_t)M * HEXT * 2);
  half_t* ctx_hi  = (half_t*)take((size_t)M * CDIM * 2);
  half_t* ctx_lo  = (half_t*)take((size_t)M * CDIM * 2);
  float*  c_f     = (float*)take((size_t)M * HDIM * 4);
  float*  gctx    = (float*)take((size_t)M * GDIM * 4);
  float*  stats   = (float*)take((size_t)M * 2 * 4);
  float*  pos_f   = (float*)take((size_t)M * 2 * 4);
  float*  delta   = (float*)take((size_t)M * 2 * 4);

  // static builders (once)
  build_whh_cat<<<(GDIM * (KGT/4) + 255) / 256, 256, 0, stream>>>(W_hh, W_ih, Whh_cat);
  build_wih_cat<<<(GDIM * 384 + 255) / 256, 256, 0, stream>>>(W_ih, Wih_cat);
  build_bias<<<(GDIM + 255) / 256, 256, 0, stream>>>(b_ih, b_hh, bias_i);
  build_w1g_cat<<<HDIM, 256, 0, stream>>>(W1, ln_g, ln_b, b1, W1g_cat, v1, v2);
  build_wc_cat<<<HDIM, 128, 0, stream>>>(Wh, Wh_cat);
  build_wc_cat<<<HDIM, 128, 0, stream>>>(Wc, Wc_cat);

  const dim3 blk(256);
  for (int chunk = 0; chunk < NC; ++chunk) {
    const size_t base = (size_t)chunk * M;
    cvt_split<<<(M * CDIM / 4 + 255) / 256, 256, 0, stream>>>(
        context + base * CDIM, ctx_hi, ctx_lo, M * CDIM / 4);
    // h0 = tanh(ctx@Wh^T + bh) split-out; c0 = tanh(ctx@Wc^T + bc) fp32;
    // gctx = ctx@Wihc^T + (b_ih + b_hh) fp32 (interleaved cols)
    gemm3_pre<1, true ><<<dim3(M/128, HDIM/128), blk, 0, stream>>>(
        ctx_hi, ctx_lo, Wh_cat, bh, nullptr, h0hi, h0lo, 0);
    gemm3_pre<1, false><<<dim3(M/128, HDIM/128), blk, 0, stream>>>(
        ctx_hi, ctx_lo, Wc_cat, bc, c_f, nullptr, nullptr, HDIM);
    gemm3_pre<0, false><<<dim3(M/128, GDIM/128), blk, 0, stream>>>(
        ctx_hi, ctx_lo, Wih_cat, bias_i, gctx, nullptr, nullptr, GDIM);
    init_chunk<<<(M + 255) / 256, 256, 0, stream>>>(
        last_pos + base * 2, last_delta + base * 2, pos_f,
        h0hi, h0lo, h1hi, h1lo, stats, delta, M);

    const half_t* hAhi = h0hi; const half_t* hAlo = h0lo;
    half_t* hBhi = h1hi; half_t* hBlo = h1lo;
    for (int t = 0; t < TSTEP; ++t) {
      gemm_gates_cell<<<dim3(M/128, GDIM/128), blk, 0, stream>>>(
          hAhi, hAlo, Whh_cat, gctx, c_f, hBhi, hBlo, stats);
      gemm_mlp<<<dim3(M/128, HDIM/128), blk, 0, stream>>>(
          hBhi, hBlo, W1g_cat, stats, v1, v2, W2, delta);
      finalize_step<<<(M + 255) / 256, 256, 0, stream>>>(
          delta, b2, pos_f, out + base * TSTEP * 2, hBhi, hBlo, stats, delta, t, M);
      half_t* th = hBhi; hBhi = (half_t*)hAhi; hAhi = th;
      half_t* tl = hBlo; hBlo = (half_t*)hAlo; hAlo = tl;
    }
  }
  (void)in_sizes; (void)n_in; (void)out_size;
}

// Round 8
// 48978.482 us; speedup vs baseline: 1.2587x; 1.1953x over previous
//
#include <hip/hip_runtime.h>
#include <math.h>

constexpr int BATCH = 16384;
constexpr int CDIM  = 512;
constexpr int HDIM  = 1024;
constexpr int GDIM  = 4096;   // 4*H
constexpr int TSTEP = 60;
// split-fp16 compensation: x = hi + lo*2^-11 (lo stored pre-scaled by 2^11).
// GEMM = [hi x Wlo_s | lo_s x Whi] (acc *= 2^-11) + [hi x Whi]
constexpr float LOSC  = 2048.0f;       // 2^11
constexpr float ILOSC = 1.0f / 2048.0f;

typedef _Float16 half_t;
typedef _Float16 halfx8 __attribute__((ext_vector_type(8)));
typedef _Float16 halfx4 __attribute__((ext_vector_type(4)));
typedef float    f32x4  __attribute__((ext_vector_type(4)));

__device__ __forceinline__ void async_cp16(const void* g, void* l) {
  __builtin_amdgcn_global_load_lds((__attribute__((address_space(1))) void*)g,
                                   (__attribute__((address_space(3))) void*)l,
                                   16, 0, 0);
}

__device__ __forceinline__ half_t hi16(float x) { return (half_t)x; }
__device__ __forceinline__ half_t lo16(float x) {    // pre-scaled residual
  return (half_t)((x - (float)((half_t)x)) * LOSC);
}
__device__ __forceinline__ float sigf(float x) { return 1.0f / (1.0f + expf(-x)); }
__device__ __forceinline__ float geluf(float v) {
  return 0.5f * v * (1.0f + erff(v * 0.70710678118f));
}

// ---------- one BK=32 step, 128x128 tile ----------
__device__ __forceinline__ void kstep(f32x4 (&acc)[4][4],
    const half_t* __restrict__ A, size_t lda, int krel,
    const half_t* __restrict__ W, size_t ldw, int kw,
    half_t* sA, half_t* sB, int bm0, int bn0) {
  const int tid  = threadIdx.x;
  const int lane = tid & 63;
  const int wave = tid >> 6;
  const int wm = wave >> 1, wn = wave & 1;
  const int ar = lane >> 2;
  const int ak = (lane & 3) * 8;
  const int quad = lane >> 4;
  const int lcol = lane & 15;
#pragma unroll
  for (int cc = 0; cc < 2; ++cc) {
    const int chunk = wave + cc * 4;
    async_cp16(A + (size_t)(bm0 + chunk * 16 + ar) * lda + (krel + ak), sA + chunk * 512);
    async_cp16(W + (size_t)(bn0 + chunk * 16 + ar) * ldw + (kw + ak), sB + chunk * 512);
  }
  asm volatile("s_waitcnt vmcnt(0)" ::: "memory");
  __syncthreads();
  halfx8 af[4], bfr[4];
#pragma unroll
  for (int mi = 0; mi < 4; ++mi)
    af[mi] = *(const halfx8*)&sA[(wm * 64 + mi * 16 + lcol) * 32 + quad * 8];
#pragma unroll
  for (int ni = 0; ni < 4; ++ni)
    bfr[ni] = *(const halfx8*)&sB[(wn * 64 + ni * 16 + lcol) * 32 + quad * 8];
#pragma unroll
  for (int mi = 0; mi < 4; ++mi)
#pragma unroll
    for (int ni = 0; ni < 4; ++ni)
      acc[mi][ni] = __builtin_amdgcn_mfma_f32_16x16x32_f16(af[mi], bfr[ni], acc[mi][ni], 0, 0, 0);
  __syncthreads();
}

__device__ __forceinline__ void scale_acc4(f32x4 (&acc)[4][4], float s) {
#pragma unroll
  for (int i = 0; i < 4; ++i)
#pragma unroll
    for (int j = 0; j < 4; ++j) acc[i][j] *= s;
}

// ---------- preamble split GEMM (K=1536: [Wlo_s x Ahi | Whi x Alo_s | Whi x Ahi])
template <int ACT, bool SPLITOUT>   // ACT: 0=none 1=tanh
__global__ __launch_bounds__(256, 2)
void gemm3_pre(const half_t* __restrict__ Ahi, const half_t* __restrict__ Alo,
               const half_t* __restrict__ Wcat, const float* __restrict__ bias,
               float* __restrict__ Cf, half_t* __restrict__ Chi,
               half_t* __restrict__ Clo, int ldc) {
  __shared__ __align__(16) half_t sA[128 * 32];
  __shared__ __align__(16) half_t sB[128 * 32];
  const int tid = threadIdx.x;
  const int bm0 = blockIdx.x * 128, bn0 = blockIdx.y * 128;
  f32x4 acc[4][4];
#pragma unroll
  for (int i = 0; i < 4; ++i)
#pragma unroll
    for (int j = 0; j < 4; ++j) acc[i][j] = (f32x4){0.f, 0.f, 0.f, 0.f};
#pragma unroll 1
  for (int k0 = 0; k0 < 512; k0 += 32)
    kstep(acc, Ahi, CDIM, k0, Wcat, 1536, k0, sA, sB, bm0, bn0);
#pragma unroll 1
  for (int k0 = 512; k0 < 1024; k0 += 32)
    kstep(acc, Alo, CDIM, k0 - 512, Wcat, 1536, k0, sA, sB, bm0, bn0);
  scale_acc4(acc, ILOSC);
#pragma unroll 1
  for (int k0 = 1024; k0 < 1536; k0 += 32)
    kstep(acc, Ahi, CDIM, k0 - 1024, Wcat, 1536, k0, sA, sB, bm0, bn0);

  const int lane = tid & 63, wave = tid >> 6;
  const int wm = wave >> 1, wn = wave & 1, quad = lane >> 4, lcol = lane & 15;
#pragma unroll
  for (int ni = 0; ni < 4; ++ni) {
    const int col = bn0 + wn * 64 + ni * 16 + lcol;
    const float bv = bias[col];
#pragma unroll
    for (int mi = 0; mi < 4; ++mi) {
      const int row0 = bm0 + wm * 64 + mi * 16 + quad * 4;
#pragma unroll
      for (int r = 0; r < 4; ++r) {
        float v = acc[mi][ni][r] + bv;
        if (ACT == 1) v = tanhf(v);
        const size_t idx = (size_t)(row0 + r) * ldc + col;
        if (SPLITOUT) { Chi[idx] = hi16(v); Clo[idx] = lo16(v); }
        else          { Cf[idx] = v; }
      }
    }
  }
}

// ---------- fused gates GEMM (split-K 3072, h-only) + LSTM cell + LN-stats ----------
// gctx = ctx@Wihc^T + b_ih + b_hh (fp32, interleaved cols r'=4u+g).
// extra@Wx is a rank-4 update applied in the epilogue (exact fp32).
__global__ __launch_bounds__(256, 2)
void gemm_gates_cell(const half_t* __restrict__ hAhi, const half_t* __restrict__ hAlo,
                     const half_t* __restrict__ Whh, const float* __restrict__ gctx,
                     const float* __restrict__ extra, const float* __restrict__ Wxt,
                     float* __restrict__ c, half_t* __restrict__ hBhi,
                     half_t* __restrict__ hBlo, float* __restrict__ stats) {
  __shared__ __align__(16) half_t sA[128 * 32];
  __shared__ __align__(16) half_t sB[128 * 32];
  __shared__ __align__(16) float sE[4][16 * 68];
  const int tid = threadIdx.x;
  const int bm0 = blockIdx.x * 128, bn0 = blockIdx.y * 128;
  f32x4 acc[4][4];
#pragma unroll
  for (int i = 0; i < 4; ++i)
#pragma unroll
    for (int j = 0; j < 4; ++j) acc[i][j] = (f32x4){0.f, 0.f, 0.f, 0.f};

#pragma unroll 1
  for (int k0 = 0; k0 < 1024; k0 += 32)          // hi x Wlo_s
    kstep(acc, hAhi, HDIM, k0, Whh, 3072, k0, sA, sB, bm0, bn0);
#pragma unroll 1
  for (int k0 = 1024; k0 < 2048; k0 += 32)       // lo_s x Whi
    kstep(acc, hAlo, HDIM, k0 - 1024, Whh, 3072, k0, sA, sB, bm0, bn0);
  scale_acc4(acc, ILOSC);
#pragma unroll 1
  for (int k0 = 2048; k0 < 3072; k0 += 32)       // hi x Whi
    kstep(acc, hAhi, HDIM, k0 - 2048, Whh, 3072, k0, sA, sB, bm0, bn0);

  const int lane = tid & 63, wave = tid >> 6;
  const int wm = wave >> 1, wn = wave & 1, quad = lane >> 4, lcol = lane & 15;
  float* myE = sE[wave];
  const int u = lane & 15;
  const int q = lane >> 4;
  const int j = ((bn0 + wn * 64) >> 2) + u;      // this lane's hidden unit
  const float4 wx0 = *(const float4*)(Wxt + (size_t)j * 16 + 0);
  const float4 wx1 = *(const float4*)(Wxt + (size_t)j * 16 + 4);
  const float4 wx2 = *(const float4*)(Wxt + (size_t)j * 16 + 8);
  const float4 wx3 = *(const float4*)(Wxt + (size_t)j * 16 + 12);

#pragma unroll
  for (int mi = 0; mi < 4; ++mi) {
#pragma unroll
    for (int ni = 0; ni < 4; ++ni)
#pragma unroll
      for (int r = 0; r < 4; ++r)
        myE[(quad * 4 + r) * 68 + ni * 16 + lcol] = acc[mi][ni][r];
    // same-wave DS ops are in-order: reads below see the writes above
#pragma unroll
    for (int k = 0; k < 4; ++k) {
      const int rr = q + 4 * k;
      const int row = bm0 + wm * 64 + mi * 16 + rr;
      const f32x4 gv = *(const f32x4*)&myE[rr * 68 + u * 4];  // {i,f,g,o} h-part
      const float4 gc = *(const float4*)(gctx + (size_t)row * GDIM + 4 * j);
      const float4 e  = *(const float4*)(extra + 4 * row);
      const float pi = gv[0] + gc.x + e.x*wx0.x + e.y*wx0.y + e.z*wx0.z + e.w*wx0.w;
      const float pf = gv[1] + gc.y + e.x*wx1.x + e.y*wx1.y + e.z*wx1.z + e.w*wx1.w;
      const float pg = gv[2] + gc.z + e.x*wx2.x + e.y*wx2.y + e.z*wx2.z + e.w*wx2.w;
      const float po = gv[3] + gc.w + e.x*wx3.x + e.y*wx3.y + e.z*wx3.z + e.w*wx3.w;
      const size_t cidx = (size_t)row * HDIM + j;
      const float cn = sigf(pf) * c[cidx] + sigf(pi) * tanhf(pg);
      c[cidx] = cn;
      const float vh = sigf(po) * tanhf(cn);
      hBhi[cidx] = hi16(vh);
      hBlo[cidx] = lo16(vh);
      float ps = vh, pq = vh * vh;
#pragma unroll
      for (int m = 1; m < 16; m <<= 1) {
        ps += __shfl_xor(ps, m, 64);
        pq += __shfl_xor(pq, m, 64);
      }
      if (u == 0) {
        atomicAdd(&stats[2 * row], ps);
        atomicAdd(&stats[2 * row + 1], pq);
      }
    }
  }
}

// ---------- MLP GEMM, 128x64 tile (split-K 3072): LN folded, gelu + W2-dot ----------
// 128x64 tile -> grid (M/128)x16 = 512 blocks at M=4096: 2 blocks/CU, single
// full pass (the 128x128 version gave only 256 blocks = 1/CU, ~250 TF).
// delta feeds back into the recurrence via extra(t+1) -> stays 22-bit split.
__global__ __launch_bounds__(256, 2)
void gemm_mlp64(const half_t* __restrict__ hBhi, const half_t* __restrict__ hBlo,
                const half_t* __restrict__ W1g, const float* __restrict__ stats,
                const float* __restrict__ v1, const float* __restrict__ v2,
                const float* __restrict__ W2, float* __restrict__ delta) {
  __shared__ __align__(16) half_t sA[128 * 32];
  __shared__ __align__(16) half_t sB[64 * 32];
  const int tid = threadIdx.x;
  const int lane = tid & 63;
  const int wave = tid >> 6;
  const int ar = lane >> 2;
  const int ak = (lane & 3) * 8;
  const int quad = lane >> 4;
  const int lcol = lane & 15;
  const int bm0 = blockIdx.x * 128, bn0 = blockIdx.y * 64;
  f32x4 acc[2][4];
#pragma unroll
  for (int i = 0; i < 2; ++i)
#pragma unroll
    for (int jj = 0; jj < 4; ++jj) acc[i][jj] = (f32x4){0.f, 0.f, 0.f, 0.f};

  auto kstep64 = [&](const half_t* __restrict__ A, int krel, int kw) {
#pragma unroll
    for (int cc = 0; cc < 2; ++cc) {
      const int chunk = wave + cc * 4;
      async_cp16(A + (size_t)(bm0 + chunk * 16 + ar) * HDIM + (krel + ak), sA + chunk * 512);
    }
    async_cp16(W1g + (size_t)(bn0 + wave * 16 + ar) * 3072 + (kw + ak), sB + wave * 512);
    asm volatile("s_waitcnt vmcnt(0)" ::: "memory");
    __syncthreads();
    halfx8 af[2], bfr[4];
#pragma unroll
    for (int mi = 0; mi < 2; ++mi)
      af[mi] = *(const halfx8*)&sA[(wave * 32 + mi * 16 + lcol) * 32 + quad * 8];
#pragma unroll
    for (int ni = 0; ni < 4; ++ni)
      bfr[ni] = *(const halfx8*)&sB[(ni * 16 + lcol) * 32 + quad * 8];
#pragma unroll
    for (int mi = 0; mi < 2; ++mi)
#pragma unroll
      for (int ni = 0; ni < 4; ++ni)
        acc[mi][ni] = __builtin_amdgcn_mfma_f32_16x16x32_f16(af[mi], bfr[ni], acc[mi][ni], 0, 0, 0);
    __syncthreads();
  };

#pragma unroll 1
  for (int k0 = 0; k0 < 1024; k0 += 32) kstep64(hBhi, k0, k0);            // hi x Wlo_s
#pragma unroll 1
  for (int k0 = 1024; k0 < 2048; k0 += 32) kstep64(hBlo, k0 - 1024, k0);  // lo_s x Whi
#pragma unroll
  for (int i = 0; i < 2; ++i)
#pragma unroll
    for (int jj = 0; jj < 4; ++jj) acc[i][jj] *= ILOSC;
#pragma unroll 1
  for (int k0 = 2048; k0 < 3072; k0 += 32) kstep64(hBhi, k0 - 2048, k0);  // hi x Whi

  float w2a[4], w2b[4], v1c[4], v2c[4];
#pragma unroll
  for (int ni = 0; ni < 4; ++ni) {
    const int col = bn0 + ni * 16 + lcol;
    w2a[ni] = W2[col]; w2b[ni] = W2[HDIM + col];
    v1c[ni] = v1[col]; v2c[ni] = v2[col];
  }
#pragma unroll
  for (int mi = 0; mi < 2; ++mi) {
#pragma unroll
    for (int r = 0; r < 4; ++r) {
      const int row = bm0 + wave * 32 + mi * 16 + quad * 4 + r;
      const float S = stats[2 * row], Q = stats[2 * row + 1];
      const float mu = S * (1.0f / HDIM);
      const float rs = rsqrtf(Q * (1.0f / HDIM) - mu * mu + 1e-5f);
      float d0 = 0.f, d1 = 0.f;
#pragma unroll
      for (int ni = 0; ni < 4; ++ni) {
        const float g = geluf(rs * (acc[mi][ni][r] - mu * v1c[ni]) + v2c[ni]);
        d0 += g * w2a[ni];
        d1 += g * w2b[ni];
      }
#pragma unroll
      for (int m = 1; m < 16; m <<= 1) {
        d0 += __shfl_xor(d0, m, 64);
        d1 += __shfl_xor(d1, m, 64);
      }
      if (lcol == 0) {
        atomicAdd(&delta[2 * row], d0);
        atomicAdd(&delta[2 * row + 1], d1);
      }
    }
  }
}

// ---------- pos update + out write + next-step extra + zero stats/delta ----------
__global__ __launch_bounds__(256)
void finalize_step(const float* __restrict__ delta_in, const float* __restrict__ b2,
                   float* __restrict__ pos, float* __restrict__ out,
                   float* __restrict__ extra, float* __restrict__ stats,
                   float* __restrict__ delta, int t, int M) {
  const int b = blockIdx.x * 256 + threadIdx.x;
  if (b >= M) return;
  const float dx = delta_in[2*b]   + b2[0];
  const float dy = delta_in[2*b+1] + b2[1];
  const float px = pos[2*b] + dx, py = pos[2*b+1] + dy;
  pos[2*b] = px; pos[2*b+1] = py;
  out[((size_t)b * TSTEP + t) * 2 + 0] = px;
  out[((size_t)b * TSTEP + t) * 2 + 1] = py;
  const float nrm = fmaxf(sqrtf(dx*dx + dy*dy), 1e-6f);
  *(float4*)(extra + 4 * b) = make_float4(dx, dy, dx / nrm, dy / nrm);
  stats[2*b] = 0.f; stats[2*b+1] = 0.f;
  delta[2*b] = 0.f; delta[2*b+1] = 0.f;
}

// ---------- builders ----------
__global__ __launch_bounds__(256)
void cvt_split(const float* __restrict__ s, half_t* __restrict__ dhi,
               half_t* __restrict__ dlo, int n4) {
  int i = blockIdx.x * 256 + threadIdx.x;
  if (i >= n4) return;
  const float4 v = ((const float4*)s)[i];
  halfx4 h = { hi16(v.x), hi16(v.y), hi16(v.z), hi16(v.w) };
  halfx4 l = { lo16(v.x), lo16(v.y), lo16(v.z), lo16(v.w) };
  *(halfx4*)(dhi + (size_t)i * 4) = h;
  *(halfx4*)(dlo + (size_t)i * 4) = l;
}

// Whh3 [4096][3072] = [lo_s | hi | hi] of W_hh, rows interleaved r'=4u+g
__global__ __launch_bounds__(256)
void build_whh3(const float* __restrict__ Whh, half_t* __restrict__ dst) {
  int idx = blockIdx.x * 256 + threadIdx.x;
  if (idx >= GDIM * 768) return;
  const int rp = idx / 768;
  const int k  = (idx - rp * 768) * 4;
  const int sr = (rp & 3) * HDIM + (rp >> 2);
  const bool lo = (k < 1024);
  const int kk = k & 1023;
  const float4 v = *(const float4*)(Whh + (size_t)sr * HDIM + kk);
  half_t* d = dst + (size_t)rp * 3072 + k;
  if (lo) { halfx4 o = { lo16(v.x), lo16(v.y), lo16(v.z), lo16(v.w) }; *(halfx4*)d = o; }
  else    { halfx4 o = { hi16(v.x), hi16(v.y), hi16(v.z), hi16(v.w) }; *(halfx4*)d = o; }
}

// Wxt[j][g*4+c] = W_ih[g*H+j][512+c]  (rank-4 extra weights, fp32)
__global__ __launch_bounds__(256)
void build_wx(const float* __restrict__ Wih, float* __restrict__ Wxt) {
  int rp = blockIdx.x * 256 + threadIdx.x;
  if (rp >= GDIM) return;
  const int jj = rp >> 2, g = rp & 3;
  const int sr = g * HDIM + jj;
  const float4 v = *(const float4*)(Wih + (size_t)sr * 516 + 512);
  *(float4*)(Wxt + (size_t)jj * 16 + g * 4) = v;
}

// Wih_cat [4096][1536] = [lo_s | hi | hi] of W_ih[:, :512], rows interleaved
__global__ __launch_bounds__(256)
void build_wih_cat(const float* __restrict__ Wih, half_t* __restrict__ dst) {
  int idx = blockIdx.x * 256 + threadIdx.x;
  if (idx >= GDIM * 384) return;
  const int rp = idx / 384;
  const int k  = (idx - rp * 384) * 4;
  const int sr = (rp & 3) * HDIM + (rp >> 2);
  const bool lo = (k < 512);
  const int kk = lo ? k : (k < 1024 ? k - 512 : k - 1024);
  const float4 v = *(const float4*)(Wih + (size_t)sr * 516 + kk);
  half_t* d = dst + (size_t)rp * 1536 + k;
  if (lo) { halfx4 o = { lo16(v.x), lo16(v.y), lo16(v.z), lo16(v.w) }; *(halfx4*)d = o; }
  else    { halfx4 o = { hi16(v.x), hi16(v.y), hi16(v.z), hi16(v.w) }; *(halfx4*)d = o; }
}

// bias_i[r'] = b_ih[src] + b_hh[src]
__global__ __launch_bounds__(256)
void build_bias(const float* __restrict__ b_ih, const float* __restrict__ b_hh,
                float* __restrict__ bias_i) {
  int rp = blockIdx.x * 256 + threadIdx.x;
  if (rp >= GDIM) return;
  const int sr = (rp & 3) * HDIM + (rp >> 2);
  bias_i[rp] = b_ih[sr] + b_hh[sr];
}

// W1g_cat [1024][3072] = [lo_s | hi | hi] of W1*ln_g; v1=W1g·1; v2=W1·beta + b1
__global__ __launch_bounds__(256)
void build_w1g_cat(const float* __restrict__ W1, const float* __restrict__ g,
                   const float* __restrict__ beta, const float* __restrict__ b1,
                   half_t* __restrict__ W1g, float* __restrict__ v1,
                   float* __restrict__ v2) {
  const int n = blockIdx.x;
  const int tid = threadIdx.x;
  const int k = tid * 4;
  const float4 w  = *(const float4*)(W1 + (size_t)n * HDIM + k);
  const float4 gg = *(const float4*)(g + k);
  const float4 bb = *(const float4*)(beta + k);
  const float wg0 = w.x*gg.x, wg1 = w.y*gg.y, wg2 = w.z*gg.z, wg3 = w.w*gg.w;
  halfx4 hl = { lo16(wg0), lo16(wg1), lo16(wg2), lo16(wg3) };
  halfx4 hh = { hi16(wg0), hi16(wg1), hi16(wg2), hi16(wg3) };
  *(halfx4*)(W1g + (size_t)n * 3072 + k)        = hl;
  *(halfx4*)(W1g + (size_t)n * 3072 + 1024 + k) = hh;
  *(halfx4*)(W1g + (size_t)n * 3072 + 2048 + k) = hh;
  float s1 = wg0 + wg1 + wg2 + wg3;
  float s2 = w.x*bb.x + w.y*bb.y + w.z*bb.z + w.w*bb.w;
#pragma unroll
  for (int off = 32; off > 0; off >>= 1) {
    s1 += __shfl_down(s1, off, 64);
    s2 += __shfl_down(s2, off, 64);
  }
  __shared__ float t1[4], t2[4];
  const int wv = tid >> 6, ln = tid & 63;
  if (ln == 0) { t1[wv] = s1; t2[wv] = s2; }
  __syncthreads();
  if (tid == 0) {
    v1[n] = t1[0] + t1[1] + t1[2] + t1[3];
    v2[n] = t2[0] + t2[1] + t2[2] + t2[3] + b1[n];
  }
}

// Wc_cat [1024][1536] = [lo_s | hi | hi] of a [1024][512] fp32 matrix
__global__ __launch_bounds__(128)
void build_wc_cat(const float* __restrict__ W, half_t* __restrict__ dst) {
  const int n = blockIdx.x;
  const int k = threadIdx.x * 4;
  const float4 w = *(const float4*)(W + (size_t)n * CDIM + k);
  halfx4 hl = { lo16(w.x), lo16(w.y), lo16(w.z), lo16(w.w) };
  halfx4 hh = { hi16(w.x), hi16(w.y), hi16(w.z), hi16(w.w) };
  *(halfx4*)(dst + (size_t)n * 1536 + k)        = hl;
  *(halfx4*)(dst + (size_t)n * 1536 + 512 + k)  = hh;
  *(halfx4*)(dst + (size_t)n * 1536 + 1024 + k) = hh;
}

__global__ __launch_bounds__(256)
void init_chunk(const float* __restrict__ lp, const float* __restrict__ ld,
                float* __restrict__ pos, float* __restrict__ extra,
                float* __restrict__ stats, float* __restrict__ delta, int M) {
  int b = blockIdx.x * 256 + threadIdx.x;
  if (b >= M) return;
  pos[2*b]   = lp[2*b];
  pos[2*b+1] = lp[2*b+1];
  stats[2*b] = 0.f; stats[2*b+1] = 0.f;
  delta[2*b] = 0.f; delta[2*b+1] = 0.f;
  const float dx = ld[2*b], dy = ld[2*b+1];
  const float nrm = fmaxf(sqrtf(dx*dx + dy*dy), 1e-6f);
  *(float4*)(extra + 4 * b) = make_float4(dx, dy, dx / nrm, dy / nrm);
}

extern "C" void kernel_launch(void* const* d_in, const int* in_sizes, int n_in,
                              void* d_out, int out_size, void* d_ws, size_t ws_size,
                              hipStream_t stream) {
  const float* context    = (const float*)d_in[0];
  const float* last_pos   = (const float*)d_in[1];
  const float* last_delta = (const float*)d_in[2];
  const float* Wh   = (const float*)d_in[3];
  const float* bh   = (const float*)d_in[4];
  const float* Wc   = (const float*)d_in[5];
  const float* bc   = (const float*)d_in[6];
  const float* W_ih = (const float*)d_in[7];
  const float* b_ih = (const float*)d_in[8];
  const float* W_hh = (const float*)d_in[9];
  const float* b_hh = (const float*)d_in[10];
  const float* ln_g = (const float*)d_in[11];
  const float* ln_b = (const float*)d_in[12];
  const float* W1   = (const float*)d_in[13];
  const float* b1   = (const float*)d_in[14];
  const float* W2   = (const float*)d_in[15];
  const float* b2   = (const float*)d_in[16];
  float* out = (float*)d_out;

  // ---- workspace plan: static weights + per-chunk state (batch in NC chunks)
  const size_t stat_bytes =
      (size_t)GDIM * 3072 * 2 + (size_t)GDIM * 1536 * 2 + (size_t)HDIM * 3072 * 2 +
      2 * (size_t)HDIM * 1536 * 2 + (size_t)HDIM * 16 * 4 + (size_t)GDIM * 4 +
      2 * (size_t)HDIM * 4 + 16384;
  int NC = 0;
  for (int nc : {2, 4, 8, 16}) {
    const size_t M = BATCH / nc;
    const size_t chunk_bytes = 4 * M * HDIM * 2 + 2 * M * CDIM * 2 +
                               M * HDIM * 4 + (size_t)M * GDIM * 4 +
                               M * 4 * 4 + 3 * M * 2 * 4 + 16384;
    if (stat_bytes + chunk_bytes <= ws_size) { NC = nc; break; }
  }
  if (NC == 0) return;   // ws too small: stub-identical absmax = diagnostic
  const int M = BATCH / NC;

  char* w = (char*)d_ws;
  auto take = [&](size_t bytes) {
    char* p = w;
    w += (bytes + 255) & ~(size_t)255;
    return p;
  };
  half_t* Whh3    = (half_t*)take((size_t)GDIM * 3072 * 2);
  half_t* Wih_cat = (half_t*)take((size_t)GDIM * 1536 * 2);
  half_t* W1g_cat = (half_t*)take((size_t)HDIM * 3072 * 2);
  half_t* Wh_cat  = (half_t*)take((size_t)HDIM * 1536 * 2);
  half_t* Wc_cat  = (half_t*)take((size_t)HDIM * 1536 * 2);
  float*  Wxt     = (float*)take((size_t)HDIM * 16 * 4);
  float*  bias_i  = (float*)take((size_t)GDIM * 4);
  float*  v1      = (float*)take((size_t)HDIM * 4);
  float*  v2      = (float*)take((size_t)HDIM * 4);
  half_t* h0hi    = (half_t*)take((size_t)M * HDIM * 2);
  half_t* h0lo    = (half_t*)take((size_t)M * HDIM * 2);
  half_t* h1hi    = (half_t*)take((size_t)M * HDIM * 2);
  half_t* h1lo    = (half_t*)take((size_t)M * HDIM * 2);
  half_t* ctx_hi  = (half_t*)take((size_t)M * CDIM * 2);
  half_t* ctx_lo  = (half_t*)take((size_t)M * CDIM * 2);
  float*  c_f     = (float*)take((size_t)M * HDIM * 4);
  float*  gctx    = (float*)take((size_t)M * GDIM * 4);
  float*  extra   = (float*)take((size_t)M * 4 * 4);
  float*  stats   = (float*)take((size_t)M * 2 * 4);
  float*  pos_f   = (float*)take((size_t)M * 2 * 4);
  float*  delta   = (float*)take((size_t)M * 2 * 4);

  // static builders (once)
  build_whh3<<<(GDIM * 768 + 255) / 256, 256, 0, stream>>>(W_hh, Whh3);
  build_wx<<<(GDIM + 255) / 256, 256, 0, stream>>>(W_ih, Wxt);
  build_wih_cat<<<(GDIM * 384 + 255) / 256, 256, 0, stream>>>(W_ih, Wih_cat);
  build_bias<<<(GDIM + 255) / 256, 256, 0, stream>>>(b_ih, b_hh, bias_i);
  build_w1g_cat<<<HDIM, 256, 0, stream>>>(W1, ln_g, ln_b, b1, W1g_cat, v1, v2);
  build_wc_cat<<<HDIM, 128, 0, stream>>>(Wh, Wh_cat);
  build_wc_cat<<<HDIM, 128, 0, stream>>>(Wc, Wc_cat);

  const dim3 blk(256);
  for (int chunk = 0; chunk < NC; ++chunk) {
    const size_t base = (size_t)chunk * M;
    cvt_split<<<(M * CDIM / 4 + 255) / 256, 256, 0, stream>>>(
        context + base * CDIM, ctx_hi, ctx_lo, M * CDIM / 4);
    // h0 = tanh(ctx@Wh^T + bh) split-out; c0 = tanh(ctx@Wc^T + bc) fp32;
    // gctx = ctx@Wihc^T + (b_ih + b_hh) fp32 (interleaved cols)
    gemm3_pre<1, true ><<<dim3(M/128, HDIM/128), blk, 0, stream>>>(
        ctx_hi, ctx_lo, Wh_cat, bh, nullptr, h0hi, h0lo, HDIM);
    gemm3_pre<1, false><<<dim3(M/128, HDIM/128), blk, 0, stream>>>(
        ctx_hi, ctx_lo, Wc_cat, bc, c_f, nullptr, nullptr, HDIM);
    gemm3_pre<0, false><<<dim3(M/128, GDIM/128), blk, 0, stream>>>(
        ctx_hi, ctx_lo, Wih_cat, bias_i, gctx, nullptr, nullptr, GDIM);
    init_chunk<<<(M + 255) / 256, 256, 0, stream>>>(
        last_pos + base * 2, last_delta + base * 2, pos_f, extra, stats, delta, M);

    const half_t* hAhi = h0hi; const half_t* hAlo = h0lo;
    half_t* hBhi = h1hi; half_t* hBlo = h1lo;
    for (int t = 0; t < TSTEP; ++t) {
      gemm_gates_cell<<<dim3(M/128, GDIM/128), blk, 0, stream>>>(
          hAhi, hAlo, Whh3, gctx, extra, Wxt, c_f, hBhi, hBlo, stats);
      gemm_mlp64<<<dim3(M/128, HDIM/64), blk, 0, stream>>>(
          hBhi, hBlo, W1g_cat, stats, v1, v2, W2, delta);
      finalize_step<<<(M + 255) / 256, 256, 0, stream>>>(
          delta, b2, pos_f, out + base * TSTEP * 2, extra, stats, delta, t, M);
      half_t* th = hBhi; hBhi = (half_t*)hAhi; hAhi = th;
      half_t* tl = hBlo; hBlo = (half_t*)hAlo; hAlo = tl;
    }
  }
  (void)in_sizes; (void)n_in; (void)out_size;
}

// Round 9
// 48665.262 us; speedup vs baseline: 1.2668x; 1.0064x over previous
//
#include <hip/hip_runtime.h>
#include <math.h>

constexpr int BATCH = 16384;
constexpr int CDIM  = 512;
constexpr int HDIM  = 1024;
constexpr int GDIM  = 4096;   // 4*H
constexpr int TSTEP = 60;
// split-fp16 compensation: x = hi + lo*2^-11 (lo stored pre-scaled by 2^11).
// GEMM = [hi x Wlo_s | lo_s x Whi] (acc *= 2^-11) + [hi x Whi]
constexpr float LOSC  = 2048.0f;       // 2^11
constexpr float ILOSC = 1.0f / 2048.0f;

typedef _Float16 half_t;
typedef _Float16 halfx8 __attribute__((ext_vector_type(8)));
typedef _Float16 halfx4 __attribute__((ext_vector_type(4)));
typedef float    f32x4  __attribute__((ext_vector_type(4)));

__device__ __forceinline__ void async_cp16(const void* g, void* l) {
  __builtin_amdgcn_global_load_lds((__attribute__((address_space(1))) void*)g,
                                   (__attribute__((address_space(3))) void*)l,
                                   16, 0, 0);
}

__device__ __forceinline__ half_t hi16(float x) { return (half_t)x; }
__device__ __forceinline__ half_t lo16(float x) {    // pre-scaled residual
  return (half_t)((x - (float)((half_t)x)) * LOSC);
}
__device__ __forceinline__ float sigf(float x) { return 1.0f / (1.0f + expf(-x)); }
__device__ __forceinline__ float geluf(float v) {
  return 0.5f * v * (1.0f + erff(v * 0.70710678118f));
}

// XCD-aware tile swizzle: linear block ids round-robin XCDs (id % 8). Remap so
// XCD j only touches n-tiles [j*gy/8, (j+1)*gy/8): its W stripes fit 4MB L2,
// and gy/8 consecutive slots share one m-tile (A stripe L2-reused). Bijection.
__device__ __forceinline__ void swizzle_tiles(int& mt, int& nt) {
  const int gx = gridDim.x, gy = gridDim.y;
  if (gy & 7) { mt = blockIdx.x; nt = blockIdx.y; return; }
  const int lin = blockIdx.y * gx + blockIdx.x;
  const int xcd = lin & 7;
  const int slot = lin >> 3;
  const int npx = gy >> 3;
  nt = xcd * npx + (slot % npx);
  mt = slot / npx;
}

// ---------- one BK=32 step, 128x128 tile ----------
__device__ __forceinline__ void kstep(f32x4 (&acc)[4][4],
    const half_t* __restrict__ A, size_t lda, int krel,
    const half_t* __restrict__ W, size_t ldw, int kw,
    half_t* sA, half_t* sB, int bm0, int bn0) {
  const int tid  = threadIdx.x;
  const int lane = tid & 63;
  const int wave = tid >> 6;
  const int wm = wave >> 1, wn = wave & 1;
  const int ar = lane >> 2;
  const int ak = (lane & 3) * 8;
  const int quad = lane >> 4;
  const int lcol = lane & 15;
#pragma unroll
  for (int cc = 0; cc < 2; ++cc) {
    const int chunk = wave + cc * 4;
    async_cp16(A + (size_t)(bm0 + chunk * 16 + ar) * lda + (krel + ak), sA + chunk * 512);
    async_cp16(W + (size_t)(bn0 + chunk * 16 + ar) * ldw + (kw + ak), sB + chunk * 512);
  }
  asm volatile("s_waitcnt vmcnt(0)" ::: "memory");
  __syncthreads();
  halfx8 af[4], bfr[4];
#pragma unroll
  for (int mi = 0; mi < 4; ++mi)
    af[mi] = *(const halfx8*)&sA[(wm * 64 + mi * 16 + lcol) * 32 + quad * 8];
#pragma unroll
  for (int ni = 0; ni < 4; ++ni)
    bfr[ni] = *(const halfx8*)&sB[(wn * 64 + ni * 16 + lcol) * 32 + quad * 8];
#pragma unroll
  for (int mi = 0; mi < 4; ++mi)
#pragma unroll
    for (int ni = 0; ni < 4; ++ni)
      acc[mi][ni] = __builtin_amdgcn_mfma_f32_16x16x32_f16(af[mi], bfr[ni], acc[mi][ni], 0, 0, 0);
  __syncthreads();
}

__device__ __forceinline__ void scale_acc4(f32x4 (&acc)[4][4], float s) {
#pragma unroll
  for (int i = 0; i < 4; ++i)
#pragma unroll
    for (int j = 0; j < 4; ++j) acc[i][j] *= s;
}

// ---------- preamble split GEMM (K=1536: [Wlo_s x Ahi | Whi x Alo_s | Whi x Ahi])
template <int ACT, bool SPLITOUT>   // ACT: 0=none 1=tanh
__global__ __launch_bounds__(256, 2)
void gemm3_pre(const half_t* __restrict__ Ahi, const half_t* __restrict__ Alo,
               const half_t* __restrict__ Wcat, const float* __restrict__ bias,
               float* __restrict__ Cf, half_t* __restrict__ Chi,
               half_t* __restrict__ Clo, int ldc) {
  __shared__ __align__(16) half_t sA[128 * 32];
  __shared__ __align__(16) half_t sB[128 * 32];
  const int tid = threadIdx.x;
  int mt, nt;
  swizzle_tiles(mt, nt);
  const int bm0 = mt * 128, bn0 = nt * 128;
  f32x4 acc[4][4];
#pragma unroll
  for (int i = 0; i < 4; ++i)
#pragma unroll
    for (int j = 0; j < 4; ++j) acc[i][j] = (f32x4){0.f, 0.f, 0.f, 0.f};
#pragma unroll 1
  for (int k0 = 0; k0 < 512; k0 += 32)
    kstep(acc, Ahi, CDIM, k0, Wcat, 1536, k0, sA, sB, bm0, bn0);
#pragma unroll 1
  for (int k0 = 512; k0 < 1024; k0 += 32)
    kstep(acc, Alo, CDIM, k0 - 512, Wcat, 1536, k0, sA, sB, bm0, bn0);
  scale_acc4(acc, ILOSC);
#pragma unroll 1
  for (int k0 = 1024; k0 < 1536; k0 += 32)
    kstep(acc, Ahi, CDIM, k0 - 1024, Wcat, 1536, k0, sA, sB, bm0, bn0);

  const int lane = tid & 63, wave = tid >> 6;
  const int wm = wave >> 1, wn = wave & 1, quad = lane >> 4, lcol = lane & 15;
#pragma unroll
  for (int ni = 0; ni < 4; ++ni) {
    const int col = bn0 + wn * 64 + ni * 16 + lcol;
    const float bv = bias[col];
#pragma unroll
    for (int mi = 0; mi < 4; ++mi) {
      const int row0 = bm0 + wm * 64 + mi * 16 + quad * 4;
#pragma unroll
      for (int r = 0; r < 4; ++r) {
        float v = acc[mi][ni][r] + bv;
        if (ACT == 1) v = tanhf(v);
        const size_t idx = (size_t)(row0 + r) * ldc + col;
        if (SPLITOUT) { Chi[idx] = hi16(v); Clo[idx] = lo16(v); }
        else          { Cf[idx] = v; }
      }
    }
  }
}

// ---------- fused gates GEMM (split-K 3072, h-only) + LSTM cell + LN-stats ----------
// gctx = ctx@Wihc^T + b_ih + b_hh (fp32, interleaved cols r'=4u+g).
// extra@Wx is a rank-4 update applied in the epilogue (exact fp32).
__global__ __launch_bounds__(256, 2)
void gemm_gates_cell(const half_t* __restrict__ hAhi, const half_t* __restrict__ hAlo,
                     const half_t* __restrict__ Whh, const float* __restrict__ gctx,
                     const float* __restrict__ extra, const float* __restrict__ Wxt,
                     float* __restrict__ c, half_t* __restrict__ hBhi,
                     half_t* __restrict__ hBlo, float* __restrict__ stats) {
  __shared__ __align__(16) half_t sA[128 * 32];
  __shared__ __align__(16) half_t sB[128 * 32];
  __shared__ __align__(16) float sE[4][16 * 68];
  const int tid = threadIdx.x;
  int mt, nt;
  swizzle_tiles(mt, nt);
  const int bm0 = mt * 128, bn0 = nt * 128;
  f32x4 acc[4][4];
#pragma unroll
  for (int i = 0; i < 4; ++i)
#pragma unroll
    for (int j = 0; j < 4; ++j) acc[i][j] = (f32x4){0.f, 0.f, 0.f, 0.f};

#pragma unroll 1
  for (int k0 = 0; k0 < 1024; k0 += 32)          // hi x Wlo_s
    kstep(acc, hAhi, HDIM, k0, Whh, 3072, k0, sA, sB, bm0, bn0);
#pragma unroll 1
  for (int k0 = 1024; k0 < 2048; k0 += 32)       // lo_s x Whi
    kstep(acc, hAlo, HDIM, k0 - 1024, Whh, 3072, k0, sA, sB, bm0, bn0);
  scale_acc4(acc, ILOSC);
#pragma unroll 1
  for (int k0 = 2048; k0 < 3072; k0 += 32)       // hi x Whi
    kstep(acc, hAhi, HDIM, k0 - 2048, Whh, 3072, k0, sA, sB, bm0, bn0);

  const int lane = tid & 63, wave = tid >> 6;
  const int wm = wave >> 1, wn = wave & 1, quad = lane >> 4, lcol = lane & 15;
  float* myE = sE[wave];
  const int u = lane & 15;
  const int q = lane >> 4;
  const int j = ((bn0 + wn * 64) >> 2) + u;      // this lane's hidden unit
  const float4 wx0 = *(const float4*)(Wxt + (size_t)j * 16 + 0);
  const float4 wx1 = *(const float4*)(Wxt + (size_t)j * 16 + 4);
  const float4 wx2 = *(const float4*)(Wxt + (size_t)j * 16 + 8);
  const float4 wx3 = *(const float4*)(Wxt + (size_t)j * 16 + 12);

#pragma unroll
  for (int mi = 0; mi < 4; ++mi) {
#pragma unroll
    for (int ni = 0; ni < 4; ++ni)
#pragma unroll
      for (int r = 0; r < 4; ++r)
        myE[(quad * 4 + r) * 68 + ni * 16 + lcol] = acc[mi][ni][r];
    // same-wave DS ops are in-order: reads below see the writes above
#pragma unroll
    for (int k = 0; k < 4; ++k) {
      const int rr = q + 4 * k;
      const int row = bm0 + wm * 64 + mi * 16 + rr;
      const f32x4 gv = *(const f32x4*)&myE[rr * 68 + u * 4];  // {i,f,g,o} h-part
      const float4 gc = *(const float4*)(gctx + (size_t)row * GDIM + 4 * j);
      const float4 e  = *(const float4*)(extra + 4 * row);
      const float pi = gv[0] + gc.x + e.x*wx0.x + e.y*wx0.y + e.z*wx0.z + e.w*wx0.w;
      const float pf = gv[1] + gc.y + e.x*wx1.x + e.y*wx1.y + e.z*wx1.z + e.w*wx1.w;
      const float pg = gv[2] + gc.z + e.x*wx2.x + e.y*wx2.y + e.z*wx2.z + e.w*wx2.w;
      const float po = gv[3] + gc.w + e.x*wx3.x + e.y*wx3.y + e.z*wx3.z + e.w*wx3.w;
      const size_t cidx = (size_t)row * HDIM + j;
      const float cn = sigf(pf) * c[cidx] + sigf(pi) * tanhf(pg);
      c[cidx] = cn;
      const float vh = sigf(po) * tanhf(cn);
      hBhi[cidx] = hi16(vh);
      hBlo[cidx] = lo16(vh);
      float ps = vh, pq = vh * vh;
#pragma unroll
      for (int m = 1; m < 16; m <<= 1) {
        ps += __shfl_xor(ps, m, 64);
        pq += __shfl_xor(pq, m, 64);
      }
      if (u == 0) {
        atomicAdd(&stats[2 * row], ps);
        atomicAdd(&stats[2 * row + 1], pq);
      }
    }
  }
}

// ---------- MLP GEMM, 128x64 tile (split-K 3072): LN folded, gelu + W2-dot ----------
// delta feeds back into the recurrence via extra(t+1) -> stays 22-bit split.
__global__ __launch_bounds__(256, 2)
void gemm_mlp64(const half_t* __restrict__ hBhi, const half_t* __restrict__ hBlo,
                const half_t* __restrict__ W1g, const float* __restrict__ stats,
                const float* __restrict__ v1, const float* __restrict__ v2,
                const float* __restrict__ W2, float* __restrict__ delta) {
  __shared__ __align__(16) half_t sA[128 * 32];
  __shared__ __align__(16) half_t sB[64 * 32];
  const int tid = threadIdx.x;
  const int lane = tid & 63;
  const int wave = tid >> 6;
  const int ar = lane >> 2;
  const int ak = (lane & 3) * 8;
  const int quad = lane >> 4;
  const int lcol = lane & 15;
  int mt, nt;
  swizzle_tiles(mt, nt);
  const int bm0 = mt * 128, bn0 = nt * 64;
  f32x4 acc[2][4];
#pragma unroll
  for (int i = 0; i < 2; ++i)
#pragma unroll
    for (int jj = 0; jj < 4; ++jj) acc[i][jj] = (f32x4){0.f, 0.f, 0.f, 0.f};

  auto kstep64 = [&](const half_t* __restrict__ A, int krel, int kw) {
#pragma unroll
    for (int cc = 0; cc < 2; ++cc) {
      const int chunk = wave + cc * 4;
      async_cp16(A + (size_t)(bm0 + chunk * 16 + ar) * HDIM + (krel + ak), sA + chunk * 512);
    }
    async_cp16(W1g + (size_t)(bn0 + wave * 16 + ar) * 3072 + (kw + ak), sB + wave * 512);
    asm volatile("s_waitcnt vmcnt(0)" ::: "memory");
    __syncthreads();
    halfx8 af[2], bfr[4];
#pragma unroll
    for (int mi = 0; mi < 2; ++mi)
      af[mi] = *(const halfx8*)&sA[(wave * 32 + mi * 16 + lcol) * 32 + quad * 8];
#pragma unroll
    for (int ni = 0; ni < 4; ++ni)
      bfr[ni] = *(const halfx8*)&sB[(ni * 16 + lcol) * 32 + quad * 8];
#pragma unroll
    for (int mi = 0; mi < 2; ++mi)
#pragma unroll
      for (int ni = 0; ni < 4; ++ni)
        acc[mi][ni] = __builtin_amdgcn_mfma_f32_16x16x32_f16(af[mi], bfr[ni], acc[mi][ni], 0, 0, 0);
    __syncthreads();
  };

#pragma unroll 1
  for (int k0 = 0; k0 < 1024; k0 += 32) kstep64(hBhi, k0, k0);            // hi x Wlo_s
#pragma unroll 1
  for (int k0 = 1024; k0 < 2048; k0 += 32) kstep64(hBlo, k0 - 1024, k0);  // lo_s x Whi
#pragma unroll
  for (int i = 0; i < 2; ++i)
#pragma unroll
    for (int jj = 0; jj < 4; ++jj) acc[i][jj] *= ILOSC;
#pragma unroll 1
  for (int k0 = 2048; k0 < 3072; k0 += 32) kstep64(hBhi, k0 - 2048, k0);  // hi x Whi

  float w2a[4], w2b[4], v1c[4], v2c[4];
#pragma unroll
  for (int ni = 0; ni < 4; ++ni) {
    const int col = bn0 + ni * 16 + lcol;
    w2a[ni] = W2[col]; w2b[ni] = W2[HDIM + col];
    v1c[ni] = v1[col]; v2c[ni] = v2[col];
  }
#pragma unroll
  for (int mi = 0; mi < 2; ++mi) {
#pragma unroll
    for (int r = 0; r < 4; ++r) {
      const int row = bm0 + wave * 32 + mi * 16 + quad * 4 + r;
      const float S = stats[2 * row], Q = stats[2 * row + 1];
      const float mu = S * (1.0f / HDIM);
      const float rs = rsqrtf(Q * (1.0f / HDIM) - mu * mu + 1e-5f);
      float d0 = 0.f, d1 = 0.f;
#pragma unroll
      for (int ni = 0; ni < 4; ++ni) {
        const float g = geluf(rs * (acc[mi][ni][r] - mu * v1c[ni]) + v2c[ni]);
        d0 += g * w2a[ni];
        d1 += g * w2b[ni];
      }
#pragma unroll
      for (int m = 1; m < 16; m <<= 1) {
        d0 += __shfl_xor(d0, m, 64);
        d1 += __shfl_xor(d1, m, 64);
      }
      if (lcol == 0) {
        atomicAdd(&delta[2 * row], d0);
        atomicAdd(&delta[2 * row + 1], d1);
      }
    }
  }
}

// ---------- pos update + out write + next-step extra + zero stats/delta ----------
__global__ __launch_bounds__(256)
void finalize_step(const float* __restrict__ delta_in, const float* __restrict__ b2,
                   float* __restrict__ pos, float* __restrict__ out,
                   float* __restrict__ extra, float* __restrict__ stats,
                   float* __restrict__ delta, int t, int M) {
  const int b = blockIdx.x * 256 + threadIdx.x;
  if (b >= M) return;
  const float dx = delta_in[2*b]   + b2[0];
  const float dy = delta_in[2*b+1] + b2[1];
  const float px = pos[2*b] + dx, py = pos[2*b+1] + dy;
  pos[2*b] = px; pos[2*b+1] = py;
  out[((size_t)b * TSTEP + t) * 2 + 0] = px;
  out[((size_t)b * TSTEP + t) * 2 + 1] = py;
  const float nrm = fmaxf(sqrtf(dx*dx + dy*dy), 1e-6f);
  *(float4*)(extra + 4 * b) = make_float4(dx, dy, dx / nrm, dy / nrm);
  stats[2*b] = 0.f; stats[2*b+1] = 0.f;
  delta[2*b] = 0.f; delta[2*b+1] = 0.f;
}

// ---------- builders ----------
__global__ __launch_bounds__(256)
void cvt_split(const float* __restrict__ s, half_t* __restrict__ dhi,
               half_t* __restrict__ dlo, int n4) {
  int i = blockIdx.x * 256 + threadIdx.x;
  if (i >= n4) return;
  const float4 v = ((const float4*)s)[i];
  halfx4 h = { hi16(v.x), hi16(v.y), hi16(v.z), hi16(v.w) };
  halfx4 l = { lo16(v.x), lo16(v.y), lo16(v.z), lo16(v.w) };
  *(halfx4*)(dhi + (size_t)i * 4) = h;
  *(halfx4*)(dlo + (size_t)i * 4) = l;
}

// Whh3 [4096][3072] = [lo_s | hi | hi] of W_hh, rows interleaved r'=4u+g
__global__ __launch_bounds__(256)
void build_whh3(const float* __restrict__ Whh, half_t* __restrict__ dst) {
  int idx = blockIdx.x * 256 + threadIdx.x;
  if (idx >= GDIM * 768) return;
  const int rp = idx / 768;
  const int k  = (idx - rp * 768) * 4;
  const int sr = (rp & 3) * HDIM + (rp >> 2);
  const bool lo = (k < 1024);
  const int kk = k & 1023;
  const float4 v = *(const float4*)(Whh + (size_t)sr * HDIM + kk);
  half_t* d = dst + (size_t)rp * 3072 + k;
  if (lo) { halfx4 o = { lo16(v.x), lo16(v.y), lo16(v.z), lo16(v.w) }; *(halfx4*)d = o; }
  else    { halfx4 o = { hi16(v.x), hi16(v.y), hi16(v.z), hi16(v.w) }; *(halfx4*)d = o; }
}

// Wxt[j][g*4+c] = W_ih[g*H+j][512+c]  (rank-4 extra weights, fp32)
__global__ __launch_bounds__(256)
void build_wx(const float* __restrict__ Wih, float* __restrict__ Wxt) {
  int rp = blockIdx.x * 256 + threadIdx.x;
  if (rp >= GDIM) return;
  const int jj = rp >> 2, g = rp & 3;
  const int sr = g * HDIM + jj;
  const float4 v = *(const float4*)(Wih + (size_t)sr * 516 + 512);
  *(float4*)(Wxt + (size_t)jj * 16 + g * 4) = v;
}

// Wih_cat [4096][1536] = [lo_s | hi | hi] of W_ih[:, :512], rows interleaved
__global__ __launch_bounds__(256)
void build_wih_cat(const float* __restrict__ Wih, half_t* __restrict__ dst) {
  int idx = blockIdx.x * 256 + threadIdx.x;
  if (idx >= GDIM * 384) return;
  const int rp = idx / 384;
  const int k  = (idx - rp * 384) * 4;
  const int sr = (rp & 3) * HDIM + (rp >> 2);
  const bool lo = (k < 512);
  const int kk = lo ? k : (k < 1024 ? k - 512 : k - 1024);
  const float4 v = *(const float4*)(Wih + (size_t)sr * 516 + kk);
  half_t* d = dst + (size_t)rp * 1536 + k;
  if (lo) { halfx4 o = { lo16(v.x), lo16(v.y), lo16(v.z), lo16(v.w) }; *(halfx4*)d = o; }
  else    { halfx4 o = { hi16(v.x), hi16(v.y), hi16(v.z), hi16(v.w) }; *(halfx4*)d = o; }
}

// bias_i[r'] = b_ih[src] + b_hh[src]
__global__ __launch_bounds__(256)
void build_bias(const float* __restrict__ b_ih, const float* __restrict__ b_hh,
                float* __restrict__ bias_i) {
  int rp = blockIdx.x * 256 + threadIdx.x;
  if (rp >= GDIM) return;
  const int sr = (rp & 3) * HDIM + (rp >> 2);
  bias_i[rp] = b_ih[sr] + b_hh[sr];
}

// W1g_cat [1024][3072] = [lo_s | hi | hi] of W1*ln_g; v1=W1g·1; v2=W1·beta + b1
__global__ __launch_bounds__(256)
void build_w1g_cat(const float* __restrict__ W1, const float* __restrict__ g,
                   const float* __restrict__ beta, const float* __restrict__ b1,
                   half_t* __restrict__ W1g, float* __restrict__ v1,
                   float* __restrict__ v2) {
  const int n = blockIdx.x;
  const int tid = threadIdx.x;
  const int k = tid * 4;
  const float4 w  = *(const float4*)(W1 + (size_t)n * HDIM + k);
  const float4 gg = *(const float4*)(g + k);
  const float4 bb = *(const float4*)(beta + k);
  const float wg0 = w.x*gg.x, wg1 = w.y*gg.y, wg2 = w.z*gg.z, wg3 = w.w*gg.w;
  halfx4 hl = { lo16(wg0), lo16(wg1), lo16(wg2), lo16(wg3) };
  halfx4 hh = { hi16(wg0), hi16(wg1), hi16(wg2), hi16(wg3) };
  *(halfx4*)(W1g + (size_t)n * 3072 + k)        = hl;
  *(halfx4*)(W1g + (size_t)n * 3072 + 1024 + k) = hh;
  *(halfx4*)(W1g + (size_t)n * 3072 + 2048 + k) = hh;
  float s1 = wg0 + wg1 + wg2 + wg3;
  float s2 = w.x*bb.x + w.y*bb.y + w.z*bb.z + w.w*bb.w;
#pragma unroll
  for (int off = 32; off > 0; off >>= 1) {
    s1 += __shfl_down(s1, off, 64);
    s2 += __shfl_down(s2, off, 64);
  }
  __shared__ float t1[4], t2[4];
  const int wv = tid >> 6, ln = tid & 63;
  if (ln == 0) { t1[wv] = s1; t2[wv] = s2; }
  __syncthreads();
  if (tid == 0) {
    v1[n] = t1[0] + t1[1] + t1[2] + t1[3];
    v2[n] = t2[0] + t2[1] + t2[2] + t2[3] + b1[n];
  }
}

// Wc_cat [1024][1536] = [lo_s | hi | hi] of a [1024][512] fp32 matrix
__global__ __launch_bounds__(128)
void build_wc_cat(const float* __restrict__ W, half_t* __restrict__ dst) {
  const int n = blockIdx.x;
  const int k = threadIdx.x * 4;
  const float4 w = *(const float4*)(W + (size_t)n * CDIM + k);
  halfx4 hl = { lo16(w.x), lo16(w.y), lo16(w.z), lo16(w.w) };
  halfx4 hh = { hi16(w.x), hi16(w.y), hi16(w.z), hi16(w.w) };
  *(halfx4*)(dst + (size_t)n * 1536 + k)        = hl;
  *(halfx4*)(dst + (size_t)n * 1536 + 512 + k)  = hh;
  *(halfx4*)(dst + (size_t)n * 1536 + 1024 + k) = hh;
}

__global__ __launch_bounds__(256)
void init_chunk(const float* __restrict__ lp, const float* __restrict__ ld,
                float* __restrict__ pos, float* __restrict__ extra,
                float* __restrict__ stats, float* __restrict__ delta, int M) {
  int b = blockIdx.x * 256 + threadIdx.x;
  if (b >= M) return;
  pos[2*b]   = lp[2*b];
  pos[2*b+1] = lp[2*b+1];
  stats[2*b] = 0.f; stats[2*b+1] = 0.f;
  delta[2*b] = 0.f; delta[2*b+1] = 0.f;
  const float dx = ld[2*b], dy = ld[2*b+1];
  const float nrm = fmaxf(sqrtf(dx*dx + dy*dy), 1e-6f);
  *(float4*)(extra + 4 * b) = make_float4(dx, dy, dx / nrm, dy / nrm);
}

extern "C" void kernel_launch(void* const* d_in, const int* in_sizes, int n_in,
                              void* d_out, int out_size, void* d_ws, size_t ws_size,
                              hipStream_t stream) {
  const float* context    = (const float*)d_in[0];
  const float* last_pos   = (const float*)d_in[1];
  const float* last_delta = (const float*)d_in[2];
  const float* Wh   = (const float*)d_in[3];
  const float* bh   = (const float*)d_in[4];
  const float* Wc   = (const float*)d_in[5];
  const float* bc   = (const float*)d_in[6];
  const float* W_ih = (const float*)d_in[7];
  const float* b_ih = (const float*)d_in[8];
  const float* W_hh = (const float*)d_in[9];
  const float* b_hh = (const float*)d_in[10];
  const float* ln_g = (const float*)d_in[11];
  const float* ln_b = (const float*)d_in[12];
  const float* W1   = (const float*)d_in[13];
  const float* b1   = (const float*)d_in[14];
  const float* W2   = (const float*)d_in[15];
  const float* b2   = (const float*)d_in[16];
  float* out = (float*)d_out;

  // ---- workspace plan: static weights + per-chunk state (batch in NC chunks)
  const size_t stat_bytes =
      (size_t)GDIM * 3072 * 2 + (size_t)GDIM * 1536 * 2 + (size_t)HDIM * 3072 * 2 +
      2 * (size_t)HDIM * 1536 * 2 + (size_t)HDIM * 16 * 4 + (size_t)GDIM * 4 +
      2 * (size_t)HDIM * 4 + 16384;
  int NC = 0;
  for (int nc : {2, 4, 8, 16}) {
    const size_t M = BATCH / nc;
    const size_t chunk_bytes = 4 * M * HDIM * 2 + 2 * M * CDIM * 2 +
                               M * HDIM * 4 + (size_t)M * GDIM * 4 +
                               M * 4 * 4 + 3 * M * 2 * 4 + 16384;
    if (stat_bytes + chunk_bytes <= ws_size) { NC = nc; break; }
  }
  if (NC == 0) return;   // ws too small: stub-identical absmax = diagnostic
  const int M = BATCH / NC;

  char* w = (char*)d_ws;
  auto take = [&](size_t bytes) {
    char* p = w;
    w += (bytes + 255) & ~(size_t)255;
    return p;
  };
  half_t* Whh3    = (half_t*)take((size_t)GDIM * 3072 * 2);
  half_t* Wih_cat = (half_t*)take((size_t)GDIM * 1536 * 2);
  half_t* W1g_cat = (half_t*)take((size_t)HDIM * 3072 * 2);
  half_t* Wh_cat  = (half_t*)take((size_t)HDIM * 1536 * 2);
  half_t* Wc_cat  = (half_t*)take((size_t)HDIM * 1536 * 2);
  float*  Wxt     = (float*)take((size_t)HDIM * 16 * 4);
  float*  bias_i  = (float*)take((size_t)GDIM * 4);
  float*  v1      = (float*)take((size_t)HDIM * 4);
  float*  v2      = (float*)take((size_t)HDIM * 4);
  half_t* h0hi    = (half_t*)take((size_t)M * HDIM * 2);
  half_t* h0lo    = (half_t*)take((size_t)M * HDIM * 2);
  half_t* h1hi    = (half_t*)take((size_t)M * HDIM * 2);
  half_t* h1lo    = (half_t*)take((size_t)M * HDIM * 2);
  half_t* ctx_hi  = (half_t*)take((size_t)M * CDIM * 2);
  half_t* ctx_lo  = (half_t*)take((size_t)M * CDIM * 2);
  float*  c_f     = (float*)take((size_t)M * HDIM * 4);
  float*  gctx    = (float*)take((size_t)M * GDIM * 4);
  float*  extra   = (float*)take((size_t)M * 4 * 4);
  float*  stats   = (float*)take((size_t)M * 2 * 4);
  float*  pos_f   = (float*)take((size_t)M * 2 * 4);
  float*  delta   = (float*)take((size_t)M * 2 * 4);

  // static builders (once)
  build_whh3<<<(GDIM * 768 + 255) / 256, 256, 0, stream>>>(W_hh, Whh3);
  build_wx<<<(GDIM + 255) / 256, 256, 0, stream>>>(W_ih, Wxt);
  build_wih_cat<<<(GDIM * 384 + 255) / 256, 256, 0, stream>>>(W_ih, Wih_cat);
  build_bias<<<(GDIM + 255) / 256, 256, 0, stream>>>(b_ih, b_hh, bias_i);
  build_w1g_cat<<<HDIM, 256, 0, stream>>>(W1, ln_g, ln_b, b1, W1g_cat, v1, v2);
  build_wc_cat<<<HDIM, 128, 0, stream>>>(Wh, Wh_cat);
  build_wc_cat<<<HDIM, 128, 0, stream>>>(Wc, Wc_cat);

  const dim3 blk(256);
  for (int chunk = 0; chunk < NC; ++chunk) {
    const size_t base = (size_t)chunk * M;
    cvt_split<<<(M * CDIM / 4 + 255) / 256, 256, 0, stream>>>(
        context + base * CDIM, ctx_hi, ctx_lo, M * CDIM / 4);
    // h0 = tanh(ctx@Wh^T + bh) split-out; c0 = tanh(ctx@Wc^T + bc) fp32;
    // gctx = ctx@Wihc^T + (b_ih + b_hh) fp32 (interleaved cols)
    gemm3_pre<1, true ><<<dim3(M/128, HDIM/128), blk, 0, stream>>>(
        ctx_hi, ctx_lo, Wh_cat, bh, nullptr, h0hi, h0lo, HDIM);
    gemm3_pre<1, false><<<dim3(M/128, HDIM/128), blk, 0, stream>>>(
        ctx_hi, ctx_lo, Wc_cat, bc, c_f, nullptr, nullptr, HDIM);
    gemm3_pre<0, false><<<dim3(M/128, GDIM/128), blk, 0, stream>>>(
        ctx_hi, ctx_lo, Wih_cat, bias_i, gctx, nullptr, nullptr, GDIM);
    init_chunk<<<(M + 255) / 256, 256, 0, stream>>>(
        last_pos + base * 2, last_delta + base * 2, pos_f, extra, stats, delta, M);

    const half_t* hAhi = h0hi; const half_t* hAlo = h0lo;
    half_t* hBhi = h1hi; half_t* hBlo = h1lo;
    for (int t = 0; t < TSTEP; ++t) {
      gemm_gates_cell<<<dim3(M/128, GDIM/128), blk, 0, stream>>>(
          hAhi, hAlo, Whh3, gctx, extra, Wxt, c_f, hBhi, hBlo, stats);
      gemm_mlp64<<<dim3(M/128, HDIM/64), blk, 0, stream>>>(
          hBhi, hBlo, W1g_cat, stats, v1, v2, W2, delta);
      finalize_step<<<(M + 255) / 256, 256, 0, stream>>>(
          delta, b2, pos_f, out + base * TSTEP * 2, extra, stats, delta, t, M);
      half_t* th = hBhi; hBhi = (half_t*)hAhi; hAhi = th;
      half_t* tl = hBlo; hBlo = (half_t*)hAlo; hAlo = tl;
    }
  }
  (void)in_sizes; (void)n_in; (void)out_size;
}